// Round 18
// baseline (154.754 us; speedup 1.0000x reference)
//
#include <hip/hip_runtime.h>
#include <hip/hip_bf16.h>

#define NPIX 16384   // H*W
#define NC   48      // DIM

typedef __attribute__((ext_vector_type(16))) float f32x16;
typedef __attribute__((ext_vector_type(8))) short short8v;
typedef __attribute__((ext_vector_type(8))) unsigned short ushort8v;
typedef __attribute__((ext_vector_type(2))) unsigned int uint2v;

static __device__ __forceinline__ unsigned short f2bf(float x) {
  union { float f; unsigned u; } v; v.f = x;
  unsigned r = v.u + 0x7fffu + ((v.u >> 16) & 1u);
  return (unsigned short)(r >> 16);
}
static __device__ __forceinline__ float bf2f(unsigned short b) {
  union { unsigned u; float f; } v; v.u = ((unsigned)b) << 16;
  return v.f;
}

// ---------------- kernel 1: pointwise qkv conv -> bf16 channel-major.
// 48 outputs/block (grid 64x3): x-slice read once per 48-out group
// (was 9 groups -> 28 MB x-fetch; now 3 -> 9.4 MB). Same per-output
// accumulation order -> bit-identical.
__global__ __launch_bounds__(256) void k_qkv(const float* __restrict__ in,
                                             const float* __restrict__ w,
                                             unsigned short* __restrict__ out) {
  int p = blockIdx.x * 256 + threadIdx.x;
  int og = blockIdx.y * 48;
  __shared__ float wl[48][NC];
  for (int i = threadIdx.x; i < 48 * NC; i += 256)
    wl[i / NC][i % NC] = w[(og + i / NC) * NC + i % NC];
  __syncthreads();
  float acc[48];
#pragma unroll
  for (int j = 0; j < 48; ++j) acc[j] = 0.f;
  for (int c = 0; c < NC; ++c) {
    float xv = in[c * NPIX + p];
#pragma unroll
    for (int j = 0; j < 48; ++j) acc[j] += xv * wl[j][c];
  }
#pragma unroll
  for (int j = 0; j < 48; ++j) out[(og + j) * NPIX + p] = f2bf(acc[j]);
}

// ---------------- kernel 2: depthwise 3x3 (bf16), LDS-tiled + vectorized.
__global__ __launch_bounds__(256) void k_dwconv(const unsigned short* __restrict__ in,
                                                const float* __restrict__ w,
                                                unsigned short* __restrict__ out) {
  __shared__ unsigned short srows[18][136];
  const int o = blockIdx.y;
  const int by = blockIdx.x;   // row-tile 0..7
  const int tid = threadIdx.x;
  const float* wt = w + o * 9;
  for (int idx = tid; idx < 288; idx += 256) {
    int r = idx >> 4, cx = idx & 15;
    int gy = by * 16 + r - 1;
    ushort8v vv = {0, 0, 0, 0, 0, 0, 0, 0};
    if (gy >= 0 && gy < 128)
      vv = *(const ushort8v*)(in + o * NPIX + gy * 128 + cx * 8);
    *(ushort8v*)&srows[r][cx * 8] = vv;
  }
  __syncthreads();
  const int r = tid >> 4;            // output row within tile, 0..15
  const int x0 = (tid & 15) * 8;     // first of 8 output cols
  float row[3][10];
#pragma unroll
  for (int dy = 0; dy < 3; ++dy) {
    int lr = r + dy;
    ushort8v mid = *(const ushort8v*)&srows[lr][x0];
#pragma unroll
    for (int j = 0; j < 8; ++j) row[dy][j + 1] = bf2f(mid[j]);
    row[dy][0] = (x0 > 0) ? bf2f(srows[lr][x0 - 1]) : 0.f;
    row[dy][9] = (x0 + 8 < 128) ? bf2f(srows[lr][x0 + 8]) : 0.f;
  }
  float wv[9];
#pragma unroll
  for (int i = 0; i < 9; ++i) wv[i] = wt[i];
  unsigned short res[8];
#pragma unroll
  for (int j = 0; j < 8; ++j) {
    float acc = 0.f;
#pragma unroll
    for (int dy = 0; dy < 3; ++dy)
#pragma unroll
      for (int dx = 0; dx < 3; ++dx)
        acc += wv[dy * 3 + dx] * row[dy][j + dx];
    res[j] = f2bf(acc);
  }
  int gy = by * 16 + r;
  *(ushort8v*)(out + o * NPIX + gy * 128 + x0) = *(ushort8v*)res;
}

// ---------------- kernel 3: l2norm, q/k SPLIT across thread halves (2x TLP).
// q additionally scaled by t*log2(e) so attn softmax uses native exp2.
__global__ __launch_bounds__(256) void k_norm(const unsigned short* __restrict__ dwqb,
                                              const float* __restrict__ temp,
                                              unsigned short* __restrict__ qn,
                                              unsigned short* __restrict__ kn) {
  const int tid = threadIdx.x;
  const int p = blockIdx.x * 128 + (tid & 127);
  const int half = tid >> 7;  // 0: q, 1: k
  float t = temp[0] * 1.44269504088896f;
  const unsigned short* src = dwqb + half * 48 * NPIX;
  float v[48];
  float sq = 0.f;
#pragma unroll
  for (int c = 0; c < 48; ++c) {
    v[c] = bf2f(src[c * NPIX + p]);
    sq += v[c] * v[c];
  }
  float scale = (half == 0 ? t : 1.f) / fmaxf(sqrtf(sq), 1e-12f);
  unsigned short ob[48];
#pragma unroll
  for (int c = 0; c < 48; ++c) ob[c] = f2bf(v[c] * scale);
  unsigned short* dst = (half == 0 ? qn : kn) + p * 48;
#pragma unroll
  for (int j = 0; j < 6; ++j)
    *(ushort8v*)(dst + j * 8) = *(ushort8v*)&ob[j * 8];
}

// ---------------- kernel 4: MFMA attention NS=8 — FROZEN r11/r13-verified
// form (90.4 us, absmax 3.8e-6). Do NOT perturb this kernel's inner loop:
//   r8  launch_bounds(,4)      -> 1.25e-4 corruption
//   r14 s_setprio              -> 1.20e-4 corruption
//   r16 asm cvt_pk -> C pkbf   -> correct but +16 us (VALU bloat)
// The inline-asm cvt_pk cluster is both required for perf and the hazard
// edge; this exact schedule is the verified local optimum.
__global__ __launch_bounds__(256) void k_attn8(const unsigned short* __restrict__ qn,
                                               const unsigned short* __restrict__ kn,
                                               const unsigned short* __restrict__ vb,
                                               float* __restrict__ num) {
  __shared__ __align__(16) char smem[28672];  // K 12288 B + Vt 16384 B (1 buf)
  const int tid = threadIdx.x;
  const int lane = tid & 63, wid = tid >> 6;
  const int l31 = lane & 31, lh = lane >> 5;
  const int bidx = blockIdx.x;
  const int ks = bidx & 7;
  const int qb = bidx >> 3;
  const int qbase = qb * 128 + wid * 32;

  short8v qf[3];
#pragma unroll
  for (int s = 0; s < 3; ++s)
    qf[s] = *(const short8v*)(qn + (qbase + l31) * 48 + s * 16 + lh * 8);

  f32x16 acc[2];  // [c-block]
#pragma unroll
  for (int b = 0; b < 2; ++b)
#pragma unroll
    for (int r = 0; r < 16; ++r) acc[b][r] = 0.f;

  // t-invariant staging maps
  int kgoff[3], kloff[3], vgoff[3], vloff[3];
#pragma unroll
  for (int i = 0; i < 3; ++i) {
    int chunk = tid + 256 * i;
    int key = chunk / 6, part = chunk - key * 6;
    kgoff[i] = key * 48 + part * 8;
    kloff[i] = (key * 96 + part * 16) ^ ((key & 7) << 4);
    int c2 = chunk >> 4, kp = chunk & 15;
    vgoff[i] = c2 * NPIX + kp * 8;
    vloff[i] = 12288 + ((c2 * 256 + kp * 16) ^ ((c2 & 15) << 4));
  }

  // Vt pad rows 48..63: row 48 = ones (den), rest zero. Written once.
  {
    int c = 48 + (tid >> 4), kp = tid & 15;
    unsigned short val = (c == 48) ? (unsigned short)0x3F80 : (unsigned short)0;
    ushort8v vv = {val, val, val, val, val, val, val, val};
    *(ushort8v*)(smem + 12288 + ((c * 256 + kp * 16) ^ ((c & 15) << 4))) = vv;
  }
  // prologue: stage tile 0
  {
    const int m0 = ks * 2048;
#pragma unroll
    for (int i = 0; i < 3; ++i) {
      *(short8v*)(smem + kloff[i]) = *(const short8v*)(kn + m0 * 48 + kgoff[i]);
      *(short8v*)(smem + vloff[i]) = *(const short8v*)(vb + m0 + vgoff[i]);
    }
  }
  __syncthreads();

  for (int t = 0; t < 16; ++t) {
    // ---- T14 issue-early: global loads for tile t+1 into registers ----
    short8v pfk[3], pfv[3];
    const bool hasNext = (t + 1 < 16);
    if (hasNext) {
      const int m0n = ks * 2048 + (t + 1) * 128;
#pragma unroll
      for (int i = 0; i < 3; ++i) {
        pfk[i] = *(const short8v*)(kn + m0n * 48 + kgoff[i]);
        pfv[i] = *(const short8v*)(vb + m0n + vgoff[i]);
      }
    }
    // ---- compute tile t ----
#pragma unroll
    for (int kb = 0; kb < 128; kb += 32) {
      f32x16 sacc;
#pragma unroll
      for (int r = 0; r < 16; ++r) sacc[r] = 0.f;
      int key = kb + l31;
#pragma unroll
      for (int s = 0; s < 3; ++s) {
        short8v kf = *(const short8v*)(smem +
            ((key * 96 + s * 32 + lh * 16) ^ ((key & 7) << 4)));
        sacc = __builtin_amdgcn_mfma_f32_32x32x16_bf16(kf, qf[s], sacc, 0, 0, 0);
      }
      float p[16];
#pragma unroll
      for (int r = 0; r < 16; ++r) p[r] = __builtin_amdgcn_exp2f(sacc[r]);
#pragma unroll
      for (int h = 0; h < 2; ++h) {
        unsigned a0, a1, b0, b1;
        asm("v_cvt_pk_bf16_f32 %0, %1, %2" : "=v"(a0) : "v"(p[8 * h + 0]), "v"(p[8 * h + 1]));
        asm("v_cvt_pk_bf16_f32 %0, %1, %2" : "=v"(a1) : "v"(p[8 * h + 2]), "v"(p[8 * h + 3]));
        asm("v_cvt_pk_bf16_f32 %0, %1, %2" : "=v"(b0) : "v"(p[8 * h + 4]), "v"(p[8 * h + 5]));
        asm("v_cvt_pk_bf16_f32 %0, %1, %2" : "=v"(b1) : "v"(p[8 * h + 6]), "v"(p[8 * h + 7]));
        uint2v s0 = __builtin_amdgcn_permlane32_swap(a0, b0, false, false);
        uint2v s1 = __builtin_amdgcn_permlane32_swap(a1, b1, false, false);
        union { unsigned u[4]; short8v v; } pa;
        pa.u[0] = s0[0]; pa.u[1] = s1[0]; pa.u[2] = s0[1]; pa.u[3] = s1[1];
        int kbase = kb + 16 * h + 8 * lh;
        short8v vf0 = *(const short8v*)(smem + 12288 +
            ((l31 * 256 + kbase * 2) ^ ((l31 & 15) << 4)));
        acc[0] = __builtin_amdgcn_mfma_f32_32x32x16_bf16(pa.v, vf0, acc[0], 0, 0, 0);
        int c1 = 32 + l31;
        short8v vf1 = *(const short8v*)(smem + 12288 +
            ((c1 * 256 + kbase * 2) ^ ((c1 & 15) << 4)));
        acc[1] = __builtin_amdgcn_mfma_f32_32x32x16_bf16(pa.v, vf1, acc[1], 0, 0, 0);
      }
    }
    __syncthreads();  // all waves done READING tile t
    // ---- T14 write-late: park prefetched tile t+1 ----
    if (hasNext) {
#pragma unroll
      for (int i = 0; i < 3; ++i) {
        *(short8v*)(smem + kloff[i]) = pfk[i];
        *(short8v*)(smem + vloff[i]) = pfv[i];
      }
    }
    __syncthreads();  // writes visible before next compute
  }

  // ---- epilogue: transpose O through LDS (per-wave [32 q][52 c]), store
  __syncthreads();
  float* ot = (float*)smem + wid * (32 * 52);
#pragma unroll
  for (int r = 0; r < 16; ++r) {
    int q = (r & 3) + 8 * (r >> 2) + 4 * lh;
    ot[q * 52 + l31] = acc[0][r];
    if (l31 < 17) ot[q * 52 + 32 + l31] = acc[1][r];
  }
  __syncthreads();
  for (int idx = lane; idx < 49 * 32; idx += 64) {
    int q = idx & 31, c = idx >> 5;
    num[((ks * 49 + c) << 14) + qbase + q] = ot[q * 52 + c];
  }
}

// ---------------- kernel 5: fused combine + divide + proj -> d_out
__global__ __launch_bounds__(256) void k_combproj(const float* __restrict__ num,
                                                  const float* __restrict__ w,
                                                  float* __restrict__ out) {
  __shared__ float wl[48][48];
  __shared__ float tok[48][64];
  __shared__ float dinv[64];
  const int t = threadIdx.x;
  const int px = t & 63, grp = t >> 6;
  const int p0 = blockIdx.x * 64;
  for (int i = t; i < 48 * 48; i += 256) wl[i / 48][i % 48] = w[i];
#pragma unroll
  for (int i = 0; i < 12; ++i) {
    int c = grp * 12 + i;
    float s = 0.f;
#pragma unroll
    for (int ks = 0; ks < 8; ++ks) s += num[(ks * 49 + c) * NPIX + p0 + px];
    tok[c][px] = s;
  }
  if (grp == 0) {
    float d = 0.f;
#pragma unroll
    for (int ks = 0; ks < 8; ++ks) d += num[(ks * 49 + 48) * NPIX + p0 + px];
    dinv[px] = 1.f / d;
  }
  __syncthreads();
  float rd = dinv[px];
#pragma unroll
  for (int i = 0; i < 12; ++i) {
    int o = grp * 12 + i;
    float a = 0.f;
#pragma unroll
    for (int c = 0; c < 48; ++c) a += wl[o][c] * tok[c][px];
    out[o * NPIX + p0 + px] = a * rd;
  }
}

extern "C" void kernel_launch(void* const* d_in, const int* in_sizes, int n_in,
                              void* d_out, int out_size, void* d_ws, size_t ws_size,
                              hipStream_t stream) {
  const float* x      = (const float*)d_in[0];
  const float* qkv_w  = (const float*)d_in[1];
  const float* dw_w   = (const float*)d_in[2];
  const float* proj_w = (const float*)d_in[3];
  const float* temp   = (const float*)d_in[4];

  // workspace layout (bytes), peak 33.55 MB (proven available r9-r16):
  //   qn   bf16 [16384][48] @ 0         (dead after attn)
  //   kn   bf16 [16384][48] @ 1572864   (dead after attn)
  //   dwqb bf16 [144][16384] @ 3145728  (ch 96..143 = vb, live in attn)
  //   qkvb bf16 [144][16384] @ 7864320  (dead after dwconv)
  //   num  f32  [8][49][16384] @ 7864320 (overlays dead qkvb)
  char* wsb = (char*)d_ws;
  unsigned short* qn   = (unsigned short*)wsb;
  unsigned short* kn   = (unsigned short*)(wsb + 1572864);
  unsigned short* dwqb = (unsigned short*)(wsb + 3145728);
  unsigned short* vb   = dwqb + 96 * NPIX;
  unsigned short* qkvb = (unsigned short*)(wsb + 7864320);
  float* num  = (float*)(wsb + 7864320);

  k_qkv<<<dim3(64, 3), 256, 0, stream>>>(x, qkv_w, qkvb);
  k_dwconv<<<dim3(8, 144), 256, 0, stream>>>(qkvb, dw_w, dwqb);
  k_norm<<<dim3(128), 256, 0, stream>>>(dwqb, temp, qn, kn);
  k_attn8<<<dim3(1024), 256, 0, stream>>>(qn, kn, vb, num);
  k_combproj<<<dim3(256), 256, 0, stream>>>(num, proj_w, (float*)d_out);
}

// Round 19
// 124.571 us; speedup vs baseline: 1.2423x; 1.2423x over previous
//
#include <hip/hip_runtime.h>
#include <hip/hip_bf16.h>

#define NPIX 16384   // H*W
#define NC   48      // DIM

typedef __attribute__((ext_vector_type(16))) float f32x16;
typedef __attribute__((ext_vector_type(8))) short short8v;
typedef __attribute__((ext_vector_type(8))) unsigned short ushort8v;
typedef __attribute__((ext_vector_type(2))) unsigned int uint2v;

static __device__ __forceinline__ unsigned short f2bf(float x) {
  union { float f; unsigned u; } v; v.f = x;
  unsigned r = v.u + 0x7fffu + ((v.u >> 16) & 1u);
  return (unsigned short)(r >> 16);
}
static __device__ __forceinline__ float bf2f(unsigned short b) {
  union { unsigned u; float f; } v; v.u = ((unsigned)b) << 16;
  return v.f;
}

// ---------------- kernel 1: pointwise qkv conv -> bf16 channel-major.
// 16 outputs/block, grid (64,9) = 576 blocks (>= 1 block/CU is what matters;
// the 9x x re-read is L2/L3-absorbed — r17's 48-out/192-block "fix" idled
// 25% of CUs and regressed 30 us).
__global__ __launch_bounds__(256) void k_qkv(const float* __restrict__ in,
                                             const float* __restrict__ w,
                                             unsigned short* __restrict__ out) {
  int p = blockIdx.x * 256 + threadIdx.x;
  int og = blockIdx.y * 16;
  __shared__ float wl[16][NC];
  for (int i = threadIdx.x; i < 16 * NC; i += 256)
    wl[i / NC][i % NC] = w[(og + i / NC) * NC + i % NC];
  __syncthreads();
  float acc[16];
#pragma unroll
  for (int j = 0; j < 16; ++j) acc[j] = 0.f;
  for (int c = 0; c < NC; ++c) {
    float xv = in[c * NPIX + p];
#pragma unroll
    for (int j = 0; j < 16; ++j) acc[j] += xv * wl[j][c];
  }
#pragma unroll
  for (int j = 0; j < 16; ++j) out[(og + j) * NPIX + p] = f2bf(acc[j]);
}

// ---------------- kernel 2: depthwise 3x3 (bf16), LDS-tiled + vectorized.
__global__ __launch_bounds__(256) void k_dwconv(const unsigned short* __restrict__ in,
                                                const float* __restrict__ w,
                                                unsigned short* __restrict__ out) {
  __shared__ unsigned short srows[18][136];
  const int o = blockIdx.y;
  const int by = blockIdx.x;   // row-tile 0..7
  const int tid = threadIdx.x;
  const float* wt = w + o * 9;
  for (int idx = tid; idx < 288; idx += 256) {
    int r = idx >> 4, cx = idx & 15;
    int gy = by * 16 + r - 1;
    ushort8v vv = {0, 0, 0, 0, 0, 0, 0, 0};
    if (gy >= 0 && gy < 128)
      vv = *(const ushort8v*)(in + o * NPIX + gy * 128 + cx * 8);
    *(ushort8v*)&srows[r][cx * 8] = vv;
  }
  __syncthreads();
  const int r = tid >> 4;            // output row within tile, 0..15
  const int x0 = (tid & 15) * 8;     // first of 8 output cols
  float row[3][10];
#pragma unroll
  for (int dy = 0; dy < 3; ++dy) {
    int lr = r + dy;
    ushort8v mid = *(const ushort8v*)&srows[lr][x0];
#pragma unroll
    for (int j = 0; j < 8; ++j) row[dy][j + 1] = bf2f(mid[j]);
    row[dy][0] = (x0 > 0) ? bf2f(srows[lr][x0 - 1]) : 0.f;
    row[dy][9] = (x0 + 8 < 128) ? bf2f(srows[lr][x0 + 8]) : 0.f;
  }
  float wv[9];
#pragma unroll
  for (int i = 0; i < 9; ++i) wv[i] = wt[i];
  unsigned short res[8];
#pragma unroll
  for (int j = 0; j < 8; ++j) {
    float acc = 0.f;
#pragma unroll
    for (int dy = 0; dy < 3; ++dy)
#pragma unroll
      for (int dx = 0; dx < 3; ++dx)
        acc += wv[dy * 3 + dx] * row[dy][j + dx];
    res[j] = f2bf(acc);
  }
  int gy = by * 16 + r;
  *(ushort8v*)(out + o * NPIX + gy * 128 + x0) = *(ushort8v*)res;
}

// ---------------- kernel 3: l2norm, q/k SPLIT across thread halves (2x TLP).
// q additionally scaled by t*log2(e) so attn softmax uses native exp2.
__global__ __launch_bounds__(256) void k_norm(const unsigned short* __restrict__ dwqb,
                                              const float* __restrict__ temp,
                                              unsigned short* __restrict__ qn,
                                              unsigned short* __restrict__ kn) {
  const int tid = threadIdx.x;
  const int p = blockIdx.x * 128 + (tid & 127);
  const int half = tid >> 7;  // 0: q, 1: k
  float t = temp[0] * 1.44269504088896f;
  const unsigned short* src = dwqb + half * 48 * NPIX;
  float v[48];
  float sq = 0.f;
#pragma unroll
  for (int c = 0; c < 48; ++c) {
    v[c] = bf2f(src[c * NPIX + p]);
    sq += v[c] * v[c];
  }
  float scale = (half == 0 ? t : 1.f) / fmaxf(sqrtf(sq), 1e-12f);
  unsigned short ob[48];
#pragma unroll
  for (int c = 0; c < 48; ++c) ob[c] = f2bf(v[c] * scale);
  unsigned short* dst = (half == 0 ? qn : kn) + p * 48;
#pragma unroll
  for (int j = 0; j < 6; ++j)
    *(ushort8v*)(dst + j * 8) = *(ushort8v*)&ob[j * 8];
}

// ---------------- kernel 4: MFMA attention NS=8 — FROZEN r11/r13-verified
// form (90.4 us, absmax 3.8e-6). Do NOT perturb this kernel's inner loop:
//   r8  launch_bounds(,4)      -> 1.25e-4 corruption
//   r14 s_setprio              -> 1.20e-4 corruption
//   r16 asm cvt_pk -> C pkbf   -> correct but +16 us (VALU bloat)
// The inline-asm cvt_pk cluster is both required for perf and the hazard
// edge; this exact schedule is the verified local optimum.
__global__ __launch_bounds__(256) void k_attn8(const unsigned short* __restrict__ qn,
                                               const unsigned short* __restrict__ kn,
                                               const unsigned short* __restrict__ vb,
                                               float* __restrict__ num) {
  __shared__ __align__(16) char smem[28672];  // K 12288 B + Vt 16384 B (1 buf)
  const int tid = threadIdx.x;
  const int lane = tid & 63, wid = tid >> 6;
  const int l31 = lane & 31, lh = lane >> 5;
  const int bidx = blockIdx.x;
  const int ks = bidx & 7;
  const int qb = bidx >> 3;
  const int qbase = qb * 128 + wid * 32;

  short8v qf[3];
#pragma unroll
  for (int s = 0; s < 3; ++s)
    qf[s] = *(const short8v*)(qn + (qbase + l31) * 48 + s * 16 + lh * 8);

  f32x16 acc[2];  // [c-block]
#pragma unroll
  for (int b = 0; b < 2; ++b)
#pragma unroll
    for (int r = 0; r < 16; ++r) acc[b][r] = 0.f;

  // t-invariant staging maps
  int kgoff[3], kloff[3], vgoff[3], vloff[3];
#pragma unroll
  for (int i = 0; i < 3; ++i) {
    int chunk = tid + 256 * i;
    int key = chunk / 6, part = chunk - key * 6;
    kgoff[i] = key * 48 + part * 8;
    kloff[i] = (key * 96 + part * 16) ^ ((key & 7) << 4);
    int c2 = chunk >> 4, kp = chunk & 15;
    vgoff[i] = c2 * NPIX + kp * 8;
    vloff[i] = 12288 + ((c2 * 256 + kp * 16) ^ ((c2 & 15) << 4));
  }

  // Vt pad rows 48..63: row 48 = ones (den), rest zero. Written once.
  {
    int c = 48 + (tid >> 4), kp = tid & 15;
    unsigned short val = (c == 48) ? (unsigned short)0x3F80 : (unsigned short)0;
    ushort8v vv = {val, val, val, val, val, val, val, val};
    *(ushort8v*)(smem + 12288 + ((c * 256 + kp * 16) ^ ((c & 15) << 4))) = vv;
  }
  // prologue: stage tile 0
  {
    const int m0 = ks * 2048;
#pragma unroll
    for (int i = 0; i < 3; ++i) {
      *(short8v*)(smem + kloff[i]) = *(const short8v*)(kn + m0 * 48 + kgoff[i]);
      *(short8v*)(smem + vloff[i]) = *(const short8v*)(vb + m0 + vgoff[i]);
    }
  }
  __syncthreads();

  for (int t = 0; t < 16; ++t) {
    // ---- T14 issue-early: global loads for tile t+1 into registers ----
    short8v pfk[3], pfv[3];
    const bool hasNext = (t + 1 < 16);
    if (hasNext) {
      const int m0n = ks * 2048 + (t + 1) * 128;
#pragma unroll
      for (int i = 0; i < 3; ++i) {
        pfk[i] = *(const short8v*)(kn + m0n * 48 + kgoff[i]);
        pfv[i] = *(const short8v*)(vb + m0n + vgoff[i]);
      }
    }
    // ---- compute tile t ----
#pragma unroll
    for (int kb = 0; kb < 128; kb += 32) {
      f32x16 sacc;
#pragma unroll
      for (int r = 0; r < 16; ++r) sacc[r] = 0.f;
      int key = kb + l31;
#pragma unroll
      for (int s = 0; s < 3; ++s) {
        short8v kf = *(const short8v*)(smem +
            ((key * 96 + s * 32 + lh * 16) ^ ((key & 7) << 4)));
        sacc = __builtin_amdgcn_mfma_f32_32x32x16_bf16(kf, qf[s], sacc, 0, 0, 0);
      }
      float p[16];
#pragma unroll
      for (int r = 0; r < 16; ++r) p[r] = __builtin_amdgcn_exp2f(sacc[r]);
#pragma unroll
      for (int h = 0; h < 2; ++h) {
        unsigned a0, a1, b0, b1;
        asm("v_cvt_pk_bf16_f32 %0, %1, %2" : "=v"(a0) : "v"(p[8 * h + 0]), "v"(p[8 * h + 1]));
        asm("v_cvt_pk_bf16_f32 %0, %1, %2" : "=v"(a1) : "v"(p[8 * h + 2]), "v"(p[8 * h + 3]));
        asm("v_cvt_pk_bf16_f32 %0, %1, %2" : "=v"(b0) : "v"(p[8 * h + 4]), "v"(p[8 * h + 5]));
        asm("v_cvt_pk_bf16_f32 %0, %1, %2" : "=v"(b1) : "v"(p[8 * h + 6]), "v"(p[8 * h + 7]));
        uint2v s0 = __builtin_amdgcn_permlane32_swap(a0, b0, false, false);
        uint2v s1 = __builtin_amdgcn_permlane32_swap(a1, b1, false, false);
        union { unsigned u[4]; short8v v; } pa;
        pa.u[0] = s0[0]; pa.u[1] = s1[0]; pa.u[2] = s0[1]; pa.u[3] = s1[1];
        int kbase = kb + 16 * h + 8 * lh;
        short8v vf0 = *(const short8v*)(smem + 12288 +
            ((l31 * 256 + kbase * 2) ^ ((l31 & 15) << 4)));
        acc[0] = __builtin_amdgcn_mfma_f32_32x32x16_bf16(pa.v, vf0, acc[0], 0, 0, 0);
        int c1 = 32 + l31;
        short8v vf1 = *(const short8v*)(smem + 12288 +
            ((c1 * 256 + kbase * 2) ^ ((c1 & 15) << 4)));
        acc[1] = __builtin_amdgcn_mfma_f32_32x32x16_bf16(pa.v, vf1, acc[1], 0, 0, 0);
      }
    }
    __syncthreads();  // all waves done READING tile t
    // ---- T14 write-late: park prefetched tile t+1 ----
    if (hasNext) {
#pragma unroll
      for (int i = 0; i < 3; ++i) {
        *(short8v*)(smem + kloff[i]) = pfk[i];
        *(short8v*)(smem + vloff[i]) = pfv[i];
      }
    }
    __syncthreads();  // writes visible before next compute
  }

  // ---- epilogue: transpose O through LDS (per-wave [32 q][52 c]), store
  __syncthreads();
  float* ot = (float*)smem + wid * (32 * 52);
#pragma unroll
  for (int r = 0; r < 16; ++r) {
    int q = (r & 3) + 8 * (r >> 2) + 4 * lh;
    ot[q * 52 + l31] = acc[0][r];
    if (l31 < 17) ot[q * 52 + 32 + l31] = acc[1][r];
  }
  __syncthreads();
  for (int idx = lane; idx < 49 * 32; idx += 64) {
    int q = idx & 31, c = idx >> 5;
    num[((ks * 49 + c) << 14) + qbase + q] = ot[q * 52 + c];
  }
}

// ---------------- kernel 5: fused combine + divide + proj -> d_out
__global__ __launch_bounds__(256) void k_combproj(const float* __restrict__ num,
                                                  const float* __restrict__ w,
                                                  float* __restrict__ out) {
  __shared__ float wl[48][48];
  __shared__ float tok[48][64];
  __shared__ float dinv[64];
  const int t = threadIdx.x;
  const int px = t & 63, grp = t >> 6;
  const int p0 = blockIdx.x * 64;
  for (int i = t; i < 48 * 48; i += 256) wl[i / 48][i % 48] = w[i];
#pragma unroll
  for (int i = 0; i < 12; ++i) {
    int c = grp * 12 + i;
    float s = 0.f;
#pragma unroll
    for (int ks = 0; ks < 8; ++ks) s += num[(ks * 49 + c) * NPIX + p0 + px];
    tok[c][px] = s;
  }
  if (grp == 0) {
    float d = 0.f;
#pragma unroll
    for (int ks = 0; ks < 8; ++ks) d += num[(ks * 49 + 48) * NPIX + p0 + px];
    dinv[px] = 1.f / d;
  }
  __syncthreads();
  float rd = dinv[px];
#pragma unroll
  for (int i = 0; i < 12; ++i) {
    int o = grp * 12 + i;
    float a = 0.f;
#pragma unroll
    for (int c = 0; c < 48; ++c) a += wl[o][c] * tok[c][px];
    out[o * NPIX + p0 + px] = a * rd;
  }
}

extern "C" void kernel_launch(void* const* d_in, const int* in_sizes, int n_in,
                              void* d_out, int out_size, void* d_ws, size_t ws_size,
                              hipStream_t stream) {
  const float* x      = (const float*)d_in[0];
  const float* qkv_w  = (const float*)d_in[1];
  const float* dw_w   = (const float*)d_in[2];
  const float* proj_w = (const float*)d_in[3];
  const float* temp   = (const float*)d_in[4];

  // workspace layout (bytes), peak 33.55 MB (proven available r9-r17):
  //   qn   bf16 [16384][48] @ 0         (dead after attn)
  //   kn   bf16 [16384][48] @ 1572864   (dead after attn)
  //   dwqb bf16 [144][16384] @ 3145728  (ch 96..143 = vb, live in attn)
  //   qkvb bf16 [144][16384] @ 7864320  (dead after dwconv)
  //   num  f32  [8][49][16384] @ 7864320 (overlays dead qkvb)
  char* wsb = (char*)d_ws;
  unsigned short* qn   = (unsigned short*)wsb;
  unsigned short* kn   = (unsigned short*)(wsb + 1572864);
  unsigned short* dwqb = (unsigned short*)(wsb + 3145728);
  unsigned short* vb   = dwqb + 96 * NPIX;
  unsigned short* qkvb = (unsigned short*)(wsb + 7864320);
  float* num  = (float*)(wsb + 7864320);

  k_qkv<<<dim3(64, 9), 256, 0, stream>>>(x, qkv_w, qkvb);
  k_dwconv<<<dim3(8, 144), 256, 0, stream>>>(qkvb, dw_w, dwqb);
  k_norm<<<dim3(128), 256, 0, stream>>>(dwqb, temp, qn, kn);
  k_attn8<<<dim3(1024), 256, 0, stream>>>(qn, kn, vb, num);
  k_combproj<<<dim3(256), 256, 0, stream>>>(num, proj_w, (float*)d_out);
}

// Round 20
// 123.698 us; speedup vs baseline: 1.2511x; 1.0071x over previous
//
#include <hip/hip_runtime.h>
#include <hip/hip_bf16.h>

#define NPIX 16384   // H*W
#define NC   48      // DIM

typedef __attribute__((ext_vector_type(16))) float f32x16;
typedef __attribute__((ext_vector_type(8))) short short8v;
typedef __attribute__((ext_vector_type(8))) unsigned short ushort8v;
typedef __attribute__((ext_vector_type(2))) unsigned int uint2v;

static __device__ __forceinline__ unsigned short f2bf(float x) {
  union { float f; unsigned u; } v; v.f = x;
  unsigned r = v.u + 0x7fffu + ((v.u >> 16) & 1u);
  return (unsigned short)(r >> 16);
}
static __device__ __forceinline__ float bf2f(unsigned short b) {
  union { unsigned u; float f; } v; v.u = ((unsigned)b) << 16;
  return v.f;
}

// ---------------- kernel 1: pointwise qkv conv -> bf16 channel-major.
__global__ __launch_bounds__(256) void k_qkv(const float* __restrict__ in,
                                             const float* __restrict__ w,
                                             unsigned short* __restrict__ out) {
  int p = blockIdx.x * 256 + threadIdx.x;
  int og = blockIdx.y * 16;
  __shared__ float wl[16][NC];
  for (int i = threadIdx.x; i < 16 * NC; i += 256)
    wl[i / NC][i % NC] = w[(og + i / NC) * NC + i % NC];
  __syncthreads();
  float acc[16];
#pragma unroll
  for (int j = 0; j < 16; ++j) acc[j] = 0.f;
  for (int c = 0; c < NC; ++c) {
    float xv = in[c * NPIX + p];
#pragma unroll
    for (int j = 0; j < 16; ++j) acc[j] += xv * wl[j][c];
  }
#pragma unroll
  for (int j = 0; j < 16; ++j) out[(og + j) * NPIX + p] = f2bf(acc[j]);
}

// ---------------- kernel 2: depthwise 3x3 (bf16), LDS-tiled + vectorized.
__global__ __launch_bounds__(256) void k_dwconv(const unsigned short* __restrict__ in,
                                                const float* __restrict__ w,
                                                unsigned short* __restrict__ out) {
  __shared__ unsigned short srows[18][136];
  const int o = blockIdx.y;
  const int by = blockIdx.x;   // row-tile 0..7
  const int tid = threadIdx.x;
  const float* wt = w + o * 9;
  for (int idx = tid; idx < 288; idx += 256) {
    int r = idx >> 4, cx = idx & 15;
    int gy = by * 16 + r - 1;
    ushort8v vv = {0, 0, 0, 0, 0, 0, 0, 0};
    if (gy >= 0 && gy < 128)
      vv = *(const ushort8v*)(in + o * NPIX + gy * 128 + cx * 8);
    *(ushort8v*)&srows[r][cx * 8] = vv;
  }
  __syncthreads();
  const int r = tid >> 4;            // output row within tile, 0..15
  const int x0 = (tid & 15) * 8;     // first of 8 output cols
  float row[3][10];
#pragma unroll
  for (int dy = 0; dy < 3; ++dy) {
    int lr = r + dy;
    ushort8v mid = *(const ushort8v*)&srows[lr][x0];
#pragma unroll
    for (int j = 0; j < 8; ++j) row[dy][j + 1] = bf2f(mid[j]);
    row[dy][0] = (x0 > 0) ? bf2f(srows[lr][x0 - 1]) : 0.f;
    row[dy][9] = (x0 + 8 < 128) ? bf2f(srows[lr][x0 + 8]) : 0.f;
  }
  float wv[9];
#pragma unroll
  for (int i = 0; i < 9; ++i) wv[i] = wt[i];
  unsigned short res[8];
#pragma unroll
  for (int j = 0; j < 8; ++j) {
    float acc = 0.f;
#pragma unroll
    for (int dy = 0; dy < 3; ++dy)
#pragma unroll
      for (int dx = 0; dx < 3; ++dx)
        acc += wv[dy * 3 + dx] * row[dy][j + dx];
    res[j] = f2bf(acc);
  }
  int gy = by * 16 + r;
  *(ushort8v*)(out + o * NPIX + gy * 128 + x0) = *(ushort8v*)res;
}

// ---------------- kernel 3: l2norm, q/k SPLIT across thread halves (2x TLP).
__global__ __launch_bounds__(256) void k_norm(const unsigned short* __restrict__ dwqb,
                                              const float* __restrict__ temp,
                                              unsigned short* __restrict__ qn,
                                              unsigned short* __restrict__ kn) {
  const int tid = threadIdx.x;
  const int p = blockIdx.x * 128 + (tid & 127);
  const int half = tid >> 7;  // 0: q, 1: k
  float t = temp[0] * 1.44269504088896f;
  const unsigned short* src = dwqb + half * 48 * NPIX;
  float v[48];
  float sq = 0.f;
#pragma unroll
  for (int c = 0; c < 48; ++c) {
    v[c] = bf2f(src[c * NPIX + p]);
    sq += v[c] * v[c];
  }
  float scale = (half == 0 ? t : 1.f) / fmaxf(sqrtf(sq), 1e-12f);
  unsigned short ob[48];
#pragma unroll
  for (int c = 0; c < 48; ++c) ob[c] = f2bf(v[c] * scale);
  unsigned short* dst = (half == 0 ? qn : kn) + p * 48;
#pragma unroll
  for (int j = 0; j < 6; ++j)
    *(ushort8v*)(dst + j * 8) = *(ushort8v*)&ob[j * 8];
}

// ---------------- kernel 4: MFMA attention NS=8 — r11/r13 inner loop
// (byte-identical compute/asm cluster) on a DOUBLE-buffer with ONE barrier
// per tile. The mid-tile barrier is dead by the disjoint-buffer invariant:
// compute reads buf[t&1] while prefetch ds_writes target buf[(t+1)&1]; the
// single end barrier orders write(bufB) -> next-iter read(bufB). This is the
// PASSED r6 structure minus a provably-redundant barrier — NOT in the
// failure families (r2/r4 wave-parity; r8/r14 inner-loop scheduling hints).
// Still NO min-waves clause; inner loop remains frozen.
__global__ __launch_bounds__(256) void k_attn8(const unsigned short* __restrict__ qn,
                                               const unsigned short* __restrict__ kn,
                                               const unsigned short* __restrict__ vb,
                                               float* __restrict__ num) {
  __shared__ __align__(16) char smem[57344];  // 2 x (K 12288 B + Vt 16384 B)
  const int tid = threadIdx.x;
  const int lane = tid & 63, wid = tid >> 6;
  const int l31 = lane & 31, lh = lane >> 5;
  const int bidx = blockIdx.x;
  const int ks = bidx & 7;
  const int qb = bidx >> 3;
  const int qbase = qb * 128 + wid * 32;

  short8v qf[3];
#pragma unroll
  for (int s = 0; s < 3; ++s)
    qf[s] = *(const short8v*)(qn + (qbase + l31) * 48 + s * 16 + lh * 8);

  f32x16 acc[2];  // [c-block]
#pragma unroll
  for (int b = 0; b < 2; ++b)
#pragma unroll
    for (int r = 0; r < 16; ++r) acc[b][r] = 0.f;

  // t-invariant staging maps (offsets relative to buffer base)
  int kgoff[3], kloff[3], vgoff[3], vloff[3];
#pragma unroll
  for (int i = 0; i < 3; ++i) {
    int chunk = tid + 256 * i;
    int key = chunk / 6, part = chunk - key * 6;
    kgoff[i] = key * 48 + part * 8;
    kloff[i] = (key * 96 + part * 16) ^ ((key & 7) << 4);
    int c2 = chunk >> 4, kp = chunk & 15;
    vgoff[i] = c2 * NPIX + kp * 8;
    vloff[i] = 12288 + ((c2 * 256 + kp * 16) ^ ((c2 & 15) << 4));
  }

  // Vt pad rows 48..63 for BOTH buffers: row 48 = ones (den), rest zero.
  for (int i = tid; i < 512; i += 256) {
    int b = i >> 8, j = i & 255;
    int c = 48 + (j >> 4), kp = j & 15;
    unsigned short val = (c == 48) ? (unsigned short)0x3F80 : (unsigned short)0;
    ushort8v vv = {val, val, val, val, val, val, val, val};
    *(ushort8v*)(smem + b * 28672 + 12288 + ((c * 256 + kp * 16) ^ ((c & 15) << 4))) = vv;
  }
  // prologue: stage tile 0 into buffer 0
  {
    const int m0 = ks * 2048;
#pragma unroll
    for (int i = 0; i < 3; ++i) {
      *(short8v*)(smem + kloff[i]) = *(const short8v*)(kn + m0 * 48 + kgoff[i]);
      *(short8v*)(smem + vloff[i]) = *(const short8v*)(vb + m0 + vgoff[i]);
    }
  }
  __syncthreads();

  for (int t = 0; t < 16; ++t) {
    char* buf = smem + (t & 1) * 28672;
    char* nbuf = smem + ((t + 1) & 1) * 28672;
    // ---- T14 issue-early: global loads for tile t+1 into registers ----
    short8v pfk[3], pfv[3];
    const bool hasNext = (t + 1 < 16);
    if (hasNext) {
      const int m0n = ks * 2048 + (t + 1) * 128;
#pragma unroll
      for (int i = 0; i < 3; ++i) {
        pfk[i] = *(const short8v*)(kn + m0n * 48 + kgoff[i]);
        pfv[i] = *(const short8v*)(vb + m0n + vgoff[i]);
      }
    }
    // ---- compute tile t from buf (inner loop byte-identical to frozen) ----
#pragma unroll
    for (int kb = 0; kb < 128; kb += 32) {
      f32x16 sacc;
#pragma unroll
      for (int r = 0; r < 16; ++r) sacc[r] = 0.f;
      int key = kb + l31;
#pragma unroll
      for (int s = 0; s < 3; ++s) {
        short8v kf = *(const short8v*)(buf +
            ((key * 96 + s * 32 + lh * 16) ^ ((key & 7) << 4)));
        sacc = __builtin_amdgcn_mfma_f32_32x32x16_bf16(kf, qf[s], sacc, 0, 0, 0);
      }
      float p[16];
#pragma unroll
      for (int r = 0; r < 16; ++r) p[r] = __builtin_amdgcn_exp2f(sacc[r]);
#pragma unroll
      for (int h = 0; h < 2; ++h) {
        unsigned a0, a1, b0, b1;
        asm("v_cvt_pk_bf16_f32 %0, %1, %2" : "=v"(a0) : "v"(p[8 * h + 0]), "v"(p[8 * h + 1]));
        asm("v_cvt_pk_bf16_f32 %0, %1, %2" : "=v"(a1) : "v"(p[8 * h + 2]), "v"(p[8 * h + 3]));
        asm("v_cvt_pk_bf16_f32 %0, %1, %2" : "=v"(b0) : "v"(p[8 * h + 4]), "v"(p[8 * h + 5]));
        asm("v_cvt_pk_bf16_f32 %0, %1, %2" : "=v"(b1) : "v"(p[8 * h + 6]), "v"(p[8 * h + 7]));
        uint2v s0 = __builtin_amdgcn_permlane32_swap(a0, b0, false, false);
        uint2v s1 = __builtin_amdgcn_permlane32_swap(a1, b1, false, false);
        union { unsigned u[4]; short8v v; } pa;
        pa.u[0] = s0[0]; pa.u[1] = s1[0]; pa.u[2] = s0[1]; pa.u[3] = s1[1];
        int kbase = kb + 16 * h + 8 * lh;
        short8v vf0 = *(const short8v*)(buf + 12288 +
            ((l31 * 256 + kbase * 2) ^ ((l31 & 15) << 4)));
        acc[0] = __builtin_amdgcn_mfma_f32_32x32x16_bf16(pa.v, vf0, acc[0], 0, 0, 0);
        int c1 = 32 + l31;
        short8v vf1 = *(const short8v*)(buf + 12288 +
            ((c1 * 256 + kbase * 2) ^ ((c1 & 15) << 4)));
        acc[1] = __builtin_amdgcn_mfma_f32_32x32x16_bf16(pa.v, vf1, acc[1], 0, 0, 0);
      }
    }
    // ---- write prefetch into the OTHER buffer (no barrier needed:
    //      disjoint from the buffer being read this iteration) ----
    if (hasNext) {
#pragma unroll
      for (int i = 0; i < 3; ++i) {
        *(short8v*)(nbuf + kloff[i]) = pfk[i];
        *(short8v*)(nbuf + vloff[i]) = pfv[i];
      }
    }
    __syncthreads();  // single barrier: write(nbuf) visible before read(nbuf)
  }

  // ---- epilogue: transpose O through LDS (per-wave [32 q][52 c]), store
  __syncthreads();
  float* ot = (float*)smem + wid * (32 * 52);
#pragma unroll
  for (int r = 0; r < 16; ++r) {
    int q = (r & 3) + 8 * (r >> 2) + 4 * lh;
    ot[q * 52 + l31] = acc[0][r];
    if (l31 < 17) ot[q * 52 + 32 + l31] = acc[1][r];
  }
  __syncthreads();
  for (int idx = lane; idx < 49 * 32; idx += 64) {
    int q = idx & 31, c = idx >> 5;
    num[((ks * 49 + c) << 14) + qbase + q] = ot[q * 52 + c];
  }
}

// ---------------- kernel 5: fused combine + divide + proj -> d_out
__global__ __launch_bounds__(256) void k_combproj(const float* __restrict__ num,
                                                  const float* __restrict__ w,
                                                  float* __restrict__ out) {
  __shared__ float wl[48][48];
  __shared__ float tok[48][64];
  __shared__ float dinv[64];
  const int t = threadIdx.x;
  const int px = t & 63, grp = t >> 6;
  const int p0 = blockIdx.x * 64;
  for (int i = t; i < 48 * 48; i += 256) wl[i / 48][i % 48] = w[i];
#pragma unroll
  for (int i = 0; i < 12; ++i) {
    int c = grp * 12 + i;
    float s = 0.f;
#pragma unroll
    for (int ks = 0; ks < 8; ++ks) s += num[(ks * 49 + c) * NPIX + p0 + px];
    tok[c][px] = s;
  }
  if (grp == 0) {
    float d = 0.f;
#pragma unroll
    for (int ks = 0; ks < 8; ++ks) d += num[(ks * 49 + 48) * NPIX + p0 + px];
    dinv[px] = 1.f / d;
  }
  __syncthreads();
  float rd = dinv[px];
#pragma unroll
  for (int i = 0; i < 12; ++i) {
    int o = grp * 12 + i;
    float a = 0.f;
#pragma unroll
    for (int c = 0; c < 48; ++c) a += wl[o][c] * tok[c][px];
    out[o * NPIX + p0 + px] = a * rd;
  }
}

extern "C" void kernel_launch(void* const* d_in, const int* in_sizes, int n_in,
                              void* d_out, int out_size, void* d_ws, size_t ws_size,
                              hipStream_t stream) {
  const float* x      = (const float*)d_in[0];
  const float* qkv_w  = (const float*)d_in[1];
  const float* dw_w   = (const float*)d_in[2];
  const float* proj_w = (const float*)d_in[3];
  const float* temp   = (const float*)d_in[4];

  // workspace layout (bytes), peak 33.55 MB (proven available r9-r18):
  //   qn   bf16 [16384][48] @ 0         (dead after attn)
  //   kn   bf16 [16384][48] @ 1572864   (dead after attn)
  //   dwqb bf16 [144][16384] @ 3145728  (ch 96..143 = vb, live in attn)
  //   qkvb bf16 [144][16384] @ 7864320  (dead after dwconv)
  //   num  f32  [8][49][16384] @ 7864320 (overlays dead qkvb)
  char* wsb = (char*)d_ws;
  unsigned short* qn   = (unsigned short*)wsb;
  unsigned short* kn   = (unsigned short*)(wsb + 1572864);
  unsigned short* dwqb = (unsigned short*)(wsb + 3145728);
  unsigned short* vb   = dwqb + 96 * NPIX;
  unsigned short* qkvb = (unsigned short*)(wsb + 7864320);
  float* num  = (float*)(wsb + 7864320);

  k_qkv<<<dim3(64, 9), 256, 0, stream>>>(x, qkv_w, qkvb);
  k_dwconv<<<dim3(8, 144), 256, 0, stream>>>(qkvb, dw_w, dwqb);
  k_norm<<<dim3(128), 256, 0, stream>>>(dwqb, temp, qn, kn);
  k_attn8<<<dim3(1024), 256, 0, stream>>>(qn, kn, vb, num);
  k_combproj<<<dim3(256), 256, 0, stream>>>(num, proj_w, (float*)d_out);
}

// Round 21
// 120.602 us; speedup vs baseline: 1.2832x; 1.0257x over previous
//
#include <hip/hip_runtime.h>
#include <hip/hip_bf16.h>

#define NPIX 16384   // H*W
#define NC   48      // DIM

typedef __attribute__((ext_vector_type(16))) float f32x16;
typedef __attribute__((ext_vector_type(8))) short short8v;
typedef __attribute__((ext_vector_type(8))) unsigned short ushort8v;
typedef __attribute__((ext_vector_type(2))) unsigned int uint2v;

static __device__ __forceinline__ unsigned short f2bf(float x) {
  union { float f; unsigned u; } v; v.f = x;
  unsigned r = v.u + 0x7fffu + ((v.u >> 16) & 1u);
  return (unsigned short)(r >> 16);
}
static __device__ __forceinline__ float bf2f(unsigned short b) {
  union { unsigned u; float f; } v; v.u = ((unsigned)b) << 16;
  return v.f;
}

// ---------------- kernel 1: pointwise qkv conv -> bf16 channel-major.
__global__ __launch_bounds__(256) void k_qkv(const float* __restrict__ in,
                                             const float* __restrict__ w,
                                             unsigned short* __restrict__ out) {
  int p = blockIdx.x * 256 + threadIdx.x;
  int og = blockIdx.y * 16;
  __shared__ float wl[16][NC];
  for (int i = threadIdx.x; i < 16 * NC; i += 256)
    wl[i / NC][i % NC] = w[(og + i / NC) * NC + i % NC];
  __syncthreads();
  float acc[16];
#pragma unroll
  for (int j = 0; j < 16; ++j) acc[j] = 0.f;
  for (int c = 0; c < NC; ++c) {
    float xv = in[c * NPIX + p];
#pragma unroll
    for (int j = 0; j < 16; ++j) acc[j] += xv * wl[j][c];
  }
#pragma unroll
  for (int j = 0; j < 16; ++j) out[(og + j) * NPIX + p] = f2bf(acc[j]);
}

// ---------------- kernel 2: depthwise 3x3 (bf16), LDS-tiled + vectorized.
__global__ __launch_bounds__(256) void k_dwconv(const unsigned short* __restrict__ in,
                                                const float* __restrict__ w,
                                                unsigned short* __restrict__ out) {
  __shared__ unsigned short srows[18][136];
  const int o = blockIdx.y;
  const int by = blockIdx.x;   // row-tile 0..7
  const int tid = threadIdx.x;
  const float* wt = w + o * 9;
  for (int idx = tid; idx < 288; idx += 256) {
    int r = idx >> 4, cx = idx & 15;
    int gy = by * 16 + r - 1;
    ushort8v vv = {0, 0, 0, 0, 0, 0, 0, 0};
    if (gy >= 0 && gy < 128)
      vv = *(const ushort8v*)(in + o * NPIX + gy * 128 + cx * 8);
    *(ushort8v*)&srows[r][cx * 8] = vv;
  }
  __syncthreads();
  const int r = tid >> 4;            // output row within tile, 0..15
  const int x0 = (tid & 15) * 8;     // first of 8 output cols
  float row[3][10];
#pragma unroll
  for (int dy = 0; dy < 3; ++dy) {
    int lr = r + dy;
    ushort8v mid = *(const ushort8v*)&srows[lr][x0];
#pragma unroll
    for (int j = 0; j < 8; ++j) row[dy][j + 1] = bf2f(mid[j]);
    row[dy][0] = (x0 > 0) ? bf2f(srows[lr][x0 - 1]) : 0.f;
    row[dy][9] = (x0 + 8 < 128) ? bf2f(srows[lr][x0 + 8]) : 0.f;
  }
  float wv[9];
#pragma unroll
  for (int i = 0; i < 9; ++i) wv[i] = wt[i];
  unsigned short res[8];
#pragma unroll
  for (int j = 0; j < 8; ++j) {
    float acc = 0.f;
#pragma unroll
    for (int dy = 0; dy < 3; ++dy)
#pragma unroll
      for (int dx = 0; dx < 3; ++dx)
        acc += wv[dy * 3 + dx] * row[dy][j + dx];
    res[j] = f2bf(acc);
  }
  int gy = by * 16 + r;
  *(ushort8v*)(out + o * NPIX + gy * 128 + x0) = *(ushort8v*)res;
}

// ---------------- kernel 3: l2norm, q/k split; grid 256 x 128 thr (1 blk/CU).
__global__ __launch_bounds__(128) void k_norm(const unsigned short* __restrict__ dwqb,
                                              const float* __restrict__ temp,
                                              unsigned short* __restrict__ qn,
                                              unsigned short* __restrict__ kn) {
  const int tid = threadIdx.x;
  const int p = blockIdx.x * 64 + (tid & 63);
  const int half = tid >> 6;  // 0: q, 1: k
  float t = temp[0] * 1.44269504088896f;
  const unsigned short* src = dwqb + half * 48 * NPIX;
  float v[48];
  float sq = 0.f;
#pragma unroll
  for (int c = 0; c < 48; ++c) {
    v[c] = bf2f(src[c * NPIX + p]);
    sq += v[c] * v[c];
  }
  float scale = (half == 0 ? t : 1.f) / fmaxf(sqrtf(sq), 1e-12f);
  unsigned short ob[48];
#pragma unroll
  for (int c = 0; c < 48; ++c) ob[c] = f2bf(v[c] * scale);
  unsigned short* dst = (half == 0 ? qn : kn) + p * 48;
#pragma unroll
  for (int j = 0; j < 6; ++j)
    *(ushort8v*)(dst + j * 8) = *(ushort8v*)&ob[j * 8];
}

// ---------------- kernel 4: MFMA attention NS=8 — FROZEN r11/r13 inner loop
// on the r19 double-buffer/1-barrier schedule (verified 89.2 us). Epilogue
// now atomicAdds partials into numS[49][16384] (epilogue edits are the safe
// family — r10/r19; inner loop untouched). atomicAdd is device-scope ->
// cross-XCD accumulation correct; float-order variation across replays is
// ~ulps, far under the validation threshold.
// Failure ledger (do NOT perturb inner-loop scheduling):
//   r8 launch_bounds(,N) / r14 s_setprio -> ~1e-4 corruption
//   r16 pkbf instead of asm cvt_pk -> correct but +16 us.
__global__ __launch_bounds__(256) void k_attn8(const unsigned short* __restrict__ qn,
                                               const unsigned short* __restrict__ kn,
                                               const unsigned short* __restrict__ vb,
                                               float* __restrict__ numS) {
  __shared__ __align__(16) char smem[57344];  // 2 x (K 12288 B + Vt 16384 B)
  const int tid = threadIdx.x;
  const int lane = tid & 63, wid = tid >> 6;
  const int l31 = lane & 31, lh = lane >> 5;
  const int bidx = blockIdx.x;
  const int ks = bidx & 7;
  const int qb = bidx >> 3;
  const int qbase = qb * 128 + wid * 32;

  short8v qf[3];
#pragma unroll
  for (int s = 0; s < 3; ++s)
    qf[s] = *(const short8v*)(qn + (qbase + l31) * 48 + s * 16 + lh * 8);

  f32x16 acc[2];  // [c-block]
#pragma unroll
  for (int b = 0; b < 2; ++b)
#pragma unroll
    for (int r = 0; r < 16; ++r) acc[b][r] = 0.f;

  // t-invariant staging maps (offsets relative to buffer base)
  int kgoff[3], kloff[3], vgoff[3], vloff[3];
#pragma unroll
  for (int i = 0; i < 3; ++i) {
    int chunk = tid + 256 * i;
    int key = chunk / 6, part = chunk - key * 6;
    kgoff[i] = key * 48 + part * 8;
    kloff[i] = (key * 96 + part * 16) ^ ((key & 7) << 4);
    int c2 = chunk >> 4, kp = chunk & 15;
    vgoff[i] = c2 * NPIX + kp * 8;
    vloff[i] = 12288 + ((c2 * 256 + kp * 16) ^ ((c2 & 15) << 4));
  }

  // Vt pad rows 48..63 for BOTH buffers: row 48 = ones (den), rest zero.
  for (int i = tid; i < 512; i += 256) {
    int b = i >> 8, j = i & 255;
    int c = 48 + (j >> 4), kp = j & 15;
    unsigned short val = (c == 48) ? (unsigned short)0x3F80 : (unsigned short)0;
    ushort8v vv = {val, val, val, val, val, val, val, val};
    *(ushort8v*)(smem + b * 28672 + 12288 + ((c * 256 + kp * 16) ^ ((c & 15) << 4))) = vv;
  }
  // prologue: stage tile 0 into buffer 0
  {
    const int m0 = ks * 2048;
#pragma unroll
    for (int i = 0; i < 3; ++i) {
      *(short8v*)(smem + kloff[i]) = *(const short8v*)(kn + m0 * 48 + kgoff[i]);
      *(short8v*)(smem + vloff[i]) = *(const short8v*)(vb + m0 + vgoff[i]);
    }
  }
  __syncthreads();

  for (int t = 0; t < 16; ++t) {
    char* buf = smem + (t & 1) * 28672;
    char* nbuf = smem + ((t + 1) & 1) * 28672;
    // ---- T14 issue-early: global loads for tile t+1 into registers ----
    short8v pfk[3], pfv[3];
    const bool hasNext = (t + 1 < 16);
    if (hasNext) {
      const int m0n = ks * 2048 + (t + 1) * 128;
#pragma unroll
      for (int i = 0; i < 3; ++i) {
        pfk[i] = *(const short8v*)(kn + m0n * 48 + kgoff[i]);
        pfv[i] = *(const short8v*)(vb + m0n + vgoff[i]);
      }
    }
    // ---- compute tile t from buf (inner loop byte-identical to frozen) ----
#pragma unroll
    for (int kb = 0; kb < 128; kb += 32) {
      f32x16 sacc;
#pragma unroll
      for (int r = 0; r < 16; ++r) sacc[r] = 0.f;
      int key = kb + l31;
#pragma unroll
      for (int s = 0; s < 3; ++s) {
        short8v kf = *(const short8v*)(buf +
            ((key * 96 + s * 32 + lh * 16) ^ ((key & 7) << 4)));
        sacc = __builtin_amdgcn_mfma_f32_32x32x16_bf16(kf, qf[s], sacc, 0, 0, 0);
      }
      float p[16];
#pragma unroll
      for (int r = 0; r < 16; ++r) p[r] = __builtin_amdgcn_exp2f(sacc[r]);
#pragma unroll
      for (int h = 0; h < 2; ++h) {
        unsigned a0, a1, b0, b1;
        asm("v_cvt_pk_bf16_f32 %0, %1, %2" : "=v"(a0) : "v"(p[8 * h + 0]), "v"(p[8 * h + 1]));
        asm("v_cvt_pk_bf16_f32 %0, %1, %2" : "=v"(a1) : "v"(p[8 * h + 2]), "v"(p[8 * h + 3]));
        asm("v_cvt_pk_bf16_f32 %0, %1, %2" : "=v"(b0) : "v"(p[8 * h + 4]), "v"(p[8 * h + 5]));
        asm("v_cvt_pk_bf16_f32 %0, %1, %2" : "=v"(b1) : "v"(p[8 * h + 6]), "v"(p[8 * h + 7]));
        uint2v s0 = __builtin_amdgcn_permlane32_swap(a0, b0, false, false);
        uint2v s1 = __builtin_amdgcn_permlane32_swap(a1, b1, false, false);
        union { unsigned u[4]; short8v v; } pa;
        pa.u[0] = s0[0]; pa.u[1] = s1[0]; pa.u[2] = s0[1]; pa.u[3] = s1[1];
        int kbase = kb + 16 * h + 8 * lh;
        short8v vf0 = *(const short8v*)(buf + 12288 +
            ((l31 * 256 + kbase * 2) ^ ((l31 & 15) << 4)));
        acc[0] = __builtin_amdgcn_mfma_f32_32x32x16_bf16(pa.v, vf0, acc[0], 0, 0, 0);
        int c1 = 32 + l31;
        short8v vf1 = *(const short8v*)(buf + 12288 +
            ((c1 * 256 + kbase * 2) ^ ((c1 & 15) << 4)));
        acc[1] = __builtin_amdgcn_mfma_f32_32x32x16_bf16(pa.v, vf1, acc[1], 0, 0, 0);
      }
    }
    // ---- write prefetch into the OTHER buffer (disjoint; no barrier) ----
    if (hasNext) {
#pragma unroll
      for (int i = 0; i < 3; ++i) {
        *(short8v*)(nbuf + kloff[i]) = pfk[i];
        *(short8v*)(nbuf + vloff[i]) = pfv[i];
      }
    }
    __syncthreads();  // single barrier: write(nbuf) visible before read(nbuf)
  }

  // ---- epilogue: transpose O through LDS, then ATOMIC-accumulate into numS
  __syncthreads();
  float* ot = (float*)smem + wid * (32 * 52);
#pragma unroll
  for (int r = 0; r < 16; ++r) {
    int q = (r & 3) + 8 * (r >> 2) + 4 * lh;
    ot[q * 52 + l31] = acc[0][r];
    if (l31 < 17) ot[q * 52 + 32 + l31] = acc[1][r];
  }
  __syncthreads();
  for (int idx = lane; idx < 49 * 32; idx += 64) {
    int q = idx & 31, c = idx >> 5;
    atomicAdd(&numS[(c << 14) + qbase + q], ot[q * 52 + c]);
  }
}

// ---------------- kernel 5: divide + proj from accumulated numS -> d_out
// (reads 3.2 MB instead of 25.7 MB; combine loop gone)
__global__ __launch_bounds__(256) void k_proj(const float* __restrict__ numS,
                                              const float* __restrict__ w,
                                              float* __restrict__ out) {
  __shared__ float wl[48][48];
  __shared__ float tok[48][64];
  __shared__ float dinv[64];
  const int t = threadIdx.x;
  const int px = t & 63, grp = t >> 6;
  const int p0 = blockIdx.x * 64;
  for (int i = t; i < 48 * 48; i += 256) wl[i / 48][i % 48] = w[i];
#pragma unroll
  for (int i = 0; i < 12; ++i) {
    int c = grp * 12 + i;
    tok[c][px] = numS[(c << 14) + p0 + px];
  }
  if (grp == 0) dinv[px] = 1.f / numS[(48 << 14) + p0 + px];
  __syncthreads();
  float rd = dinv[px];
#pragma unroll
  for (int i = 0; i < 12; ++i) {
    int o = grp * 12 + i;
    float a = 0.f;
#pragma unroll
    for (int c = 0; c < 48; ++c) a += wl[o][c] * tok[c][px];
    out[o * NPIX + p0 + px] = a * rd;
  }
}

extern "C" void kernel_launch(void* const* d_in, const int* in_sizes, int n_in,
                              void* d_out, int out_size, void* d_ws, size_t ws_size,
                              hipStream_t stream) {
  const float* x      = (const float*)d_in[0];
  const float* qkv_w  = (const float*)d_in[1];
  const float* dw_w   = (const float*)d_in[2];
  const float* proj_w = (const float*)d_in[3];
  const float* temp   = (const float*)d_in[4];

  // workspace layout (bytes), peak ~11.1 MB:
  //   qn   bf16 [16384][48] @ 0         (dead after attn)
  //   kn   bf16 [16384][48] @ 1572864   (dead after attn)
  //   dwqb bf16 [144][16384] @ 3145728  (ch 96..143 = vb, live in attn)
  //   qkvb bf16 [144][16384] @ 7864320  (dead after dwconv)
  //   numS f32  [49][16384] @ 7864320   (memset after dwconv; overlays qkvb)
  char* wsb = (char*)d_ws;
  unsigned short* qn   = (unsigned short*)wsb;
  unsigned short* kn   = (unsigned short*)(wsb + 1572864);
  unsigned short* dwqb = (unsigned short*)(wsb + 3145728);
  unsigned short* vb   = dwqb + 96 * NPIX;
  unsigned short* qkvb = (unsigned short*)(wsb + 7864320);
  float* numS = (float*)(wsb + 7864320);

  k_qkv<<<dim3(64, 9), 256, 0, stream>>>(x, qkv_w, qkvb);
  k_dwconv<<<dim3(8, 144), 256, 0, stream>>>(qkvb, dw_w, dwqb);
  k_norm<<<dim3(256), 128, 0, stream>>>(dwqb, temp, qn, kn);
  hipMemsetAsync(numS, 0, (size_t)49 * NPIX * 4, stream);
  k_attn8<<<dim3(1024), 256, 0, stream>>>(qn, kn, vb, numS);
  k_proj<<<dim3(256), 256, 0, stream>>>(numS, proj_w, (float*)d_out);
}

// Round 22
// 120.246 us; speedup vs baseline: 1.2870x; 1.0030x over previous
//
#include <hip/hip_runtime.h>
#include <hip/hip_bf16.h>

#define NPIX 16384   // H*W
#define NC   48      // DIM

typedef __attribute__((ext_vector_type(16))) float f32x16;
typedef __attribute__((ext_vector_type(8))) short short8v;
typedef __attribute__((ext_vector_type(8))) unsigned short ushort8v;
typedef __attribute__((ext_vector_type(2))) unsigned int uint2v;

static __device__ __forceinline__ unsigned short f2bf(float x) {
  union { float f; unsigned u; } v; v.f = x;
  unsigned r = v.u + 0x7fffu + ((v.u >> 16) & 1u);
  return (unsigned short)(r >> 16);
}
static __device__ __forceinline__ float bf2f(unsigned short b) {
  union { unsigned u; float f; } v; v.u = ((unsigned)b) << 16;
  return v.f;
}

// ---------------- kernel 1: pointwise qkv conv -> bf16 channel-major.
__global__ __launch_bounds__(256) void k_qkv(const float* __restrict__ in,
                                             const float* __restrict__ w,
                                             unsigned short* __restrict__ out) {
  int p = blockIdx.x * 256 + threadIdx.x;
  int og = blockIdx.y * 16;
  __shared__ float wl[16][NC];
  for (int i = threadIdx.x; i < 16 * NC; i += 256)
    wl[i / NC][i % NC] = w[(og + i / NC) * NC + i % NC];
  __syncthreads();
  float acc[16];
#pragma unroll
  for (int j = 0; j < 16; ++j) acc[j] = 0.f;
  for (int c = 0; c < NC; ++c) {
    float xv = in[c * NPIX + p];
#pragma unroll
    for (int j = 0; j < 16; ++j) acc[j] += xv * wl[j][c];
  }
#pragma unroll
  for (int j = 0; j < 16; ++j) out[(og + j) * NPIX + p] = f2bf(acc[j]);
}

// ---------------- kernel 2: depthwise 3x3 (bf16), LDS-tiled + vectorized.
__global__ __launch_bounds__(256) void k_dwconv(const unsigned short* __restrict__ in,
                                                const float* __restrict__ w,
                                                unsigned short* __restrict__ out) {
  __shared__ unsigned short srows[18][136];
  const int o = blockIdx.y;
  const int by = blockIdx.x;   // row-tile 0..7
  const int tid = threadIdx.x;
  const float* wt = w + o * 9;
  for (int idx = tid; idx < 288; idx += 256) {
    int r = idx >> 4, cx = idx & 15;
    int gy = by * 16 + r - 1;
    ushort8v vv = {0, 0, 0, 0, 0, 0, 0, 0};
    if (gy >= 0 && gy < 128)
      vv = *(const ushort8v*)(in + o * NPIX + gy * 128 + cx * 8);
    *(ushort8v*)&srows[r][cx * 8] = vv;
  }
  __syncthreads();
  const int r = tid >> 4;            // output row within tile, 0..15
  const int x0 = (tid & 15) * 8;     // first of 8 output cols
  float row[3][10];
#pragma unroll
  for (int dy = 0; dy < 3; ++dy) {
    int lr = r + dy;
    ushort8v mid = *(const ushort8v*)&srows[lr][x0];
#pragma unroll
    for (int j = 0; j < 8; ++j) row[dy][j + 1] = bf2f(mid[j]);
    row[dy][0] = (x0 > 0) ? bf2f(srows[lr][x0 - 1]) : 0.f;
    row[dy][9] = (x0 + 8 < 128) ? bf2f(srows[lr][x0 + 8]) : 0.f;
  }
  float wv[9];
#pragma unroll
  for (int i = 0; i < 9; ++i) wv[i] = wt[i];
  unsigned short res[8];
#pragma unroll
  for (int j = 0; j < 8; ++j) {
    float acc = 0.f;
#pragma unroll
    for (int dy = 0; dy < 3; ++dy)
#pragma unroll
      for (int dx = 0; dx < 3; ++dx)
        acc += wv[dy * 3 + dx] * row[dy][j + dx];
    res[j] = f2bf(acc);
  }
  int gy = by * 16 + r;
  *(ushort8v*)(out + o * NPIX + gy * 128 + x0) = *(ushort8v*)res;
}

// ---------------- kernel 3: l2norm, q/k split; grid 256 x 128 thr.
__global__ __launch_bounds__(128) void k_norm(const unsigned short* __restrict__ dwqb,
                                              const float* __restrict__ temp,
                                              unsigned short* __restrict__ qn,
                                              unsigned short* __restrict__ kn) {
  const int tid = threadIdx.x;
  const int p = blockIdx.x * 64 + (tid & 63);
  const int half = tid >> 6;  // 0: q, 1: k
  float t = temp[0] * 1.44269504088896f;
  const unsigned short* src = dwqb + half * 48 * NPIX;
  float v[48];
  float sq = 0.f;
#pragma unroll
  for (int c = 0; c < 48; ++c) {
    v[c] = bf2f(src[c * NPIX + p]);
    sq += v[c] * v[c];
  }
  float scale = (half == 0 ? t : 1.f) / fmaxf(sqrtf(sq), 1e-12f);
  unsigned short ob[48];
#pragma unroll
  for (int c = 0; c < 48; ++c) ob[c] = f2bf(v[c] * scale);
  unsigned short* dst = (half == 0 ? qn : kn) + p * 48;
#pragma unroll
  for (int j = 0; j < 6; ++j)
    *(ushort8v*)(dst + j * 8) = *(ushort8v*)&ob[j * 8];
}

// ---------------- kernel 4: MFMA attention — NS=4 (constants-only change
// from the r20-verified kernel; the NS-constant family is proven safe
// r7<->r9<->r20). FROZEN r11/r13 inner loop on the r19 double-buffer /
// 1-barrier schedule; atomic epilogue into numS[49][16384].
// grid 512: ks=bidx&3, qb=bidx>>2. XCD = bidx&7 round-robin => each XCD
// sees exactly one split value (i mod 4) — L2 locality preserved; HBM
// atomic-write traffic halves (25.7 -> 12.8 MB).
// Failure ledger (do NOT perturb inner-loop scheduling):
//   r8 launch_bounds(,N) / r14 s_setprio -> ~1e-4 corruption
//   r16 pkbf instead of asm cvt_pk -> correct but +16 us.
__global__ __launch_bounds__(256) void k_attn8(const unsigned short* __restrict__ qn,
                                               const unsigned short* __restrict__ kn,
                                               const unsigned short* __restrict__ vb,
                                               float* __restrict__ numS) {
  __shared__ __align__(16) char smem[57344];  // 2 x (K 12288 B + Vt 16384 B)
  const int tid = threadIdx.x;
  const int lane = tid & 63, wid = tid >> 6;
  const int l31 = lane & 31, lh = lane >> 5;
  const int bidx = blockIdx.x;
  const int ks = bidx & 3;
  const int qb = bidx >> 2;
  const int qbase = qb * 128 + wid * 32;

  short8v qf[3];
#pragma unroll
  for (int s = 0; s < 3; ++s)
    qf[s] = *(const short8v*)(qn + (qbase + l31) * 48 + s * 16 + lh * 8);

  f32x16 acc[2];  // [c-block]
#pragma unroll
  for (int b = 0; b < 2; ++b)
#pragma unroll
    for (int r = 0; r < 16; ++r) acc[b][r] = 0.f;

  // t-invariant staging maps (offsets relative to buffer base)
  int kgoff[3], kloff[3], vgoff[3], vloff[3];
#pragma unroll
  for (int i = 0; i < 3; ++i) {
    int chunk = tid + 256 * i;
    int key = chunk / 6, part = chunk - key * 6;
    kgoff[i] = key * 48 + part * 8;
    kloff[i] = (key * 96 + part * 16) ^ ((key & 7) << 4);
    int c2 = chunk >> 4, kp = chunk & 15;
    vgoff[i] = c2 * NPIX + kp * 8;
    vloff[i] = 12288 + ((c2 * 256 + kp * 16) ^ ((c2 & 15) << 4));
  }

  // Vt pad rows 48..63 for BOTH buffers: row 48 = ones (den), rest zero.
  for (int i = tid; i < 512; i += 256) {
    int b = i >> 8, j = i & 255;
    int c = 48 + (j >> 4), kp = j & 15;
    unsigned short val = (c == 48) ? (unsigned short)0x3F80 : (unsigned short)0;
    ushort8v vv = {val, val, val, val, val, val, val, val};
    *(ushort8v*)(smem + b * 28672 + 12288 + ((c * 256 + kp * 16) ^ ((c & 15) << 4))) = vv;
  }
  // prologue: stage tile 0 into buffer 0
  {
    const int m0 = ks * 4096;
#pragma unroll
    for (int i = 0; i < 3; ++i) {
      *(short8v*)(smem + kloff[i]) = *(const short8v*)(kn + m0 * 48 + kgoff[i]);
      *(short8v*)(smem + vloff[i]) = *(const short8v*)(vb + m0 + vgoff[i]);
    }
  }
  __syncthreads();

  for (int t = 0; t < 32; ++t) {
    char* buf = smem + (t & 1) * 28672;
    char* nbuf = smem + ((t + 1) & 1) * 28672;
    // ---- T14 issue-early: global loads for tile t+1 into registers ----
    short8v pfk[3], pfv[3];
    const bool hasNext = (t + 1 < 32);
    if (hasNext) {
      const int m0n = ks * 4096 + (t + 1) * 128;
#pragma unroll
      for (int i = 0; i < 3; ++i) {
        pfk[i] = *(const short8v*)(kn + m0n * 48 + kgoff[i]);
        pfv[i] = *(const short8v*)(vb + m0n + vgoff[i]);
      }
    }
    // ---- compute tile t from buf (inner loop byte-identical to frozen) ----
#pragma unroll
    for (int kb = 0; kb < 128; kb += 32) {
      f32x16 sacc;
#pragma unroll
      for (int r = 0; r < 16; ++r) sacc[r] = 0.f;
      int key = kb + l31;
#pragma unroll
      for (int s = 0; s < 3; ++s) {
        short8v kf = *(const short8v*)(buf +
            ((key * 96 + s * 32 + lh * 16) ^ ((key & 7) << 4)));
        sacc = __builtin_amdgcn_mfma_f32_32x32x16_bf16(kf, qf[s], sacc, 0, 0, 0);
      }
      float p[16];
#pragma unroll
      for (int r = 0; r < 16; ++r) p[r] = __builtin_amdgcn_exp2f(sacc[r]);
#pragma unroll
      for (int h = 0; h < 2; ++h) {
        unsigned a0, a1, b0, b1;
        asm("v_cvt_pk_bf16_f32 %0, %1, %2" : "=v"(a0) : "v"(p[8 * h + 0]), "v"(p[8 * h + 1]));
        asm("v_cvt_pk_bf16_f32 %0, %1, %2" : "=v"(a1) : "v"(p[8 * h + 2]), "v"(p[8 * h + 3]));
        asm("v_cvt_pk_bf16_f32 %0, %1, %2" : "=v"(b0) : "v"(p[8 * h + 4]), "v"(p[8 * h + 5]));
        asm("v_cvt_pk_bf16_f32 %0, %1, %2" : "=v"(b1) : "v"(p[8 * h + 6]), "v"(p[8 * h + 7]));
        uint2v s0 = __builtin_amdgcn_permlane32_swap(a0, b0, false, false);
        uint2v s1 = __builtin_amdgcn_permlane32_swap(a1, b1, false, false);
        union { unsigned u[4]; short8v v; } pa;
        pa.u[0] = s0[0]; pa.u[1] = s1[0]; pa.u[2] = s0[1]; pa.u[3] = s1[1];
        int kbase = kb + 16 * h + 8 * lh;
        short8v vf0 = *(const short8v*)(buf + 12288 +
            ((l31 * 256 + kbase * 2) ^ ((l31 & 15) << 4)));
        acc[0] = __builtin_amdgcn_mfma_f32_32x32x16_bf16(pa.v, vf0, acc[0], 0, 0, 0);
        int c1 = 32 + l31;
        short8v vf1 = *(const short8v*)(buf + 12288 +
            ((c1 * 256 + kbase * 2) ^ ((c1 & 15) << 4)));
        acc[1] = __builtin_amdgcn_mfma_f32_32x32x16_bf16(pa.v, vf1, acc[1], 0, 0, 0);
      }
    }
    // ---- write prefetch into the OTHER buffer (disjoint; no barrier) ----
    if (hasNext) {
#pragma unroll
      for (int i = 0; i < 3; ++i) {
        *(short8v*)(nbuf + kloff[i]) = pfk[i];
        *(short8v*)(nbuf + vloff[i]) = pfv[i];
      }
    }
    __syncthreads();  // single barrier: write(nbuf) visible before read(nbuf)
  }

  // ---- epilogue: transpose O through LDS, then ATOMIC-accumulate into numS
  __syncthreads();
  float* ot = (float*)smem + wid * (32 * 52);
#pragma unroll
  for (int r = 0; r < 16; ++r) {
    int q = (r & 3) + 8 * (r >> 2) + 4 * lh;
    ot[q * 52 + l31] = acc[0][r];
    if (l31 < 17) ot[q * 52 + 32 + l31] = acc[1][r];
  }
  __syncthreads();
  for (int idx = lane; idx < 49 * 32; idx += 64) {
    int q = idx & 31, c = idx >> 5;
    atomicAdd(&numS[(c << 14) + qbase + q], ot[q * 52 + c]);
  }
}

// ---------------- kernel 5: divide + proj from accumulated numS -> d_out
__global__ __launch_bounds__(256) void k_proj(const float* __restrict__ numS,
                                              const float* __restrict__ w,
                                              float* __restrict__ out) {
  __shared__ float wl[48][48];
  __shared__ float tok[48][64];
  __shared__ float dinv[64];
  const int t = threadIdx.x;
  const int px = t & 63, grp = t >> 6;
  const int p0 = blockIdx.x * 64;
  for (int i = t; i < 48 * 48; i += 256) wl[i / 48][i % 48] = w[i];
#pragma unroll
  for (int i = 0; i < 12; ++i) {
    int c = grp * 12 + i;
    tok[c][px] = numS[(c << 14) + p0 + px];
  }
  if (grp == 0) dinv[px] = 1.f / numS[(48 << 14) + p0 + px];
  __syncthreads();
  float rd = dinv[px];
#pragma unroll
  for (int i = 0; i < 12; ++i) {
    int o = grp * 12 + i;
    float a = 0.f;
#pragma unroll
    for (int c = 0; c < 48; ++c) a += wl[o][c] * tok[c][px];
    out[o * NPIX + p0 + px] = a * rd;
  }
}

extern "C" void kernel_launch(void* const* d_in, const int* in_sizes, int n_in,
                              void* d_out, int out_size, void* d_ws, size_t ws_size,
                              hipStream_t stream) {
  const float* x      = (const float*)d_in[0];
  const float* qkv_w  = (const float*)d_in[1];
  const float* dw_w   = (const float*)d_in[2];
  const float* proj_w = (const float*)d_in[3];
  const float* temp   = (const float*)d_in[4];

  // workspace layout (bytes), peak ~11.1 MB:
  //   qn   bf16 [16384][48] @ 0         (dead after attn)
  //   kn   bf16 [16384][48] @ 1572864   (dead after attn)
  //   dwqb bf16 [144][16384] @ 3145728  (ch 96..143 = vb, live in attn)
  //   qkvb bf16 [144][16384] @ 7864320  (dead after dwconv)
  //   numS f32  [49][16384] @ 7864320   (memset after dwconv; overlays qkvb)
  char* wsb = (char*)d_ws;
  unsigned short* qn   = (unsigned short*)wsb;
  unsigned short* kn   = (unsigned short*)(wsb + 1572864);
  unsigned short* dwqb = (unsigned short*)(wsb + 3145728);
  unsigned short* vb   = dwqb + 96 * NPIX;
  unsigned short* qkvb = (unsigned short*)(wsb + 7864320);
  float* numS = (float*)(wsb + 7864320);

  k_qkv<<<dim3(64, 9), 256, 0, stream>>>(x, qkv_w, qkvb);
  k_dwconv<<<dim3(8, 144), 256, 0, stream>>>(qkvb, dw_w, dwqb);
  k_norm<<<dim3(256), 128, 0, stream>>>(dwqb, temp, qn, kn);
  hipMemsetAsync(numS, 0, (size_t)49 * NPIX * 4, stream);
  k_attn8<<<dim3(512), 256, 0, stream>>>(qn, kn, vb, numS);
  k_proj<<<dim3(256), 256, 0, stream>>>(numS, proj_w, (float*)d_out);
}

// Round 23
// 111.189 us; speedup vs baseline: 1.3918x; 1.0814x over previous
//
#include <hip/hip_runtime.h>
#include <hip/hip_bf16.h>

#define NPIX 16384   // H*W
#define NC   48      // DIM

typedef __attribute__((ext_vector_type(16))) float f32x16;
typedef __attribute__((ext_vector_type(8))) short short8v;
typedef __attribute__((ext_vector_type(8))) unsigned short ushort8v;
typedef __attribute__((ext_vector_type(2))) unsigned int uint2v;

static __device__ __forceinline__ unsigned short f2bf(float x) {
  union { float f; unsigned u; } v; v.f = x;
  unsigned r = v.u + 0x7fffu + ((v.u >> 16) & 1u);
  return (unsigned short)(r >> 16);
}
static __device__ __forceinline__ float bf2f(unsigned short b) {
  union { unsigned u; float f; } v; v.u = ((unsigned)b) << 16;
  return v.f;
}

// ---------------- kernel 1: pointwise qkv conv -> bf16 channel-major.
__global__ __launch_bounds__(256) void k_qkv(const float* __restrict__ in,
                                             const float* __restrict__ w,
                                             unsigned short* __restrict__ out) {
  int p = blockIdx.x * 256 + threadIdx.x;
  int og = blockIdx.y * 16;
  __shared__ float wl[16][NC];
  for (int i = threadIdx.x; i < 16 * NC; i += 256)
    wl[i / NC][i % NC] = w[(og + i / NC) * NC + i % NC];
  __syncthreads();
  float acc[16];
#pragma unroll
  for (int j = 0; j < 16; ++j) acc[j] = 0.f;
  for (int c = 0; c < NC; ++c) {
    float xv = in[c * NPIX + p];
#pragma unroll
    for (int j = 0; j < 16; ++j) acc[j] += xv * wl[j][c];
  }
#pragma unroll
  for (int j = 0; j < 16; ++j) out[(og + j) * NPIX + p] = f2bf(acc[j]);
}

// ---------------- kernel 2: depthwise 3x3 (bf16), LDS-tiled + vectorized.
__global__ __launch_bounds__(256) void k_dwconv(const unsigned short* __restrict__ in,
                                                const float* __restrict__ w,
                                                unsigned short* __restrict__ out) {
  __shared__ unsigned short srows[18][136];
  const int o = blockIdx.y;
  const int by = blockIdx.x;   // row-tile 0..7
  const int tid = threadIdx.x;
  const float* wt = w + o * 9;
  for (int idx = tid; idx < 288; idx += 256) {
    int r = idx >> 4, cx = idx & 15;
    int gy = by * 16 + r - 1;
    ushort8v vv = {0, 0, 0, 0, 0, 0, 0, 0};
    if (gy >= 0 && gy < 128)
      vv = *(const ushort8v*)(in + o * NPIX + gy * 128 + cx * 8);
    *(ushort8v*)&srows[r][cx * 8] = vv;
  }
  __syncthreads();
  const int r = tid >> 4;            // output row within tile, 0..15
  const int x0 = (tid & 15) * 8;     // first of 8 output cols
  float row[3][10];
#pragma unroll
  for (int dy = 0; dy < 3; ++dy) {
    int lr = r + dy;
    ushort8v mid = *(const ushort8v*)&srows[lr][x0];
#pragma unroll
    for (int j = 0; j < 8; ++j) row[dy][j + 1] = bf2f(mid[j]);
    row[dy][0] = (x0 > 0) ? bf2f(srows[lr][x0 - 1]) : 0.f;
    row[dy][9] = (x0 + 8 < 128) ? bf2f(srows[lr][x0 + 8]) : 0.f;
  }
  float wv[9];
#pragma unroll
  for (int i = 0; i < 9; ++i) wv[i] = wt[i];
  unsigned short res[8];
#pragma unroll
  for (int j = 0; j < 8; ++j) {
    float acc = 0.f;
#pragma unroll
    for (int dy = 0; dy < 3; ++dy)
#pragma unroll
      for (int dx = 0; dx < 3; ++dx)
        acc += wv[dy * 3 + dx] * row[dy][j + dx];
    res[j] = f2bf(acc);
  }
  int gy = by * 16 + r;
  *(ushort8v*)(out + o * NPIX + gy * 128 + x0) = *(ushort8v*)res;
}

// ---------------- kernel 3: l2norm, q/k split; grid 256 x 128 thr.
__global__ __launch_bounds__(128) void k_norm(const unsigned short* __restrict__ dwqb,
                                              const float* __restrict__ temp,
                                              unsigned short* __restrict__ qn,
                                              unsigned short* __restrict__ kn) {
  const int tid = threadIdx.x;
  const int p = blockIdx.x * 64 + (tid & 63);
  const int half = tid >> 6;  // 0: q, 1: k
  float t = temp[0] * 1.44269504088896f;
  const unsigned short* src = dwqb + half * 48 * NPIX;
  float v[48];
  float sq = 0.f;
#pragma unroll
  for (int c = 0; c < 48; ++c) {
    v[c] = bf2f(src[c * NPIX + p]);
    sq += v[c] * v[c];
  }
  float scale = (half == 0 ? t : 1.f) / fmaxf(sqrtf(sq), 1e-12f);
  unsigned short ob[48];
#pragma unroll
  for (int c = 0; c < 48; ++c) ob[c] = f2bf(v[c] * scale);
  unsigned short* dst = (half == 0 ? qn : kn) + p * 48;
#pragma unroll
  for (int j = 0; j < 6; ++j)
    *(ushort8v*)(dst + j * 8) = *(ushort8v*)&ob[j * 8];
}

// ---------------- kernel 4: MFMA attention — 8 UNIFORM waves/block (512 thr),
// 256 q-rows/block, NS=8; grid 64x8=512 -> 2 blocks/CU = 4 waves/SIMD (2x).
// Ledger audit: every corrupting round (r2/r4/r8/r14) carried launch_bounds
// (,N) or setprio; 512-thread blocks were never tested WITHOUT the clause.
// This kernel: plain __launch_bounds__(512), uniform wave roles (no parity
// split, no cross-wave merge — per-wave-private epilogue), staging via the
// proven r5/r9 if-split map, FROZEN r11/r13 inner loop byte-identical,
// r19 double-buffer/1-barrier schedule, r20 atomic epilogue.
__global__ __launch_bounds__(512) void k_attn8(const unsigned short* __restrict__ qn,
                                               const unsigned short* __restrict__ kn,
                                               const unsigned short* __restrict__ vb,
                                               float* __restrict__ numS) {
  __shared__ __align__(16) char smem[57344];  // 2 x (K 12288 B + Vt 16384 B)
  const int tid = threadIdx.x;
  const int lane = tid & 63, wid = tid >> 6;   // wid 0..7
  const int l31 = lane & 31, lh = lane >> 5;
  const int bidx = blockIdx.x;
  const int ks = bidx & 7;
  const int qb = bidx >> 3;
  const int qbase = qb * 256 + wid * 32;

  short8v qf[3];
#pragma unroll
  for (int s = 0; s < 3; ++s)
    qf[s] = *(const short8v*)(qn + (qbase + l31) * 48 + s * 16 + lh * 8);

  f32x16 acc[2];  // [c-block]
#pragma unroll
  for (int b = 0; b < 2; ++b)
#pragma unroll
    for (int r = 0; r < 16; ++r) acc[b][r] = 0.f;

  // t-invariant staging maps: 1536 16B-chunks over 512 threads (3 each);
  // chunk<768 -> K (token-major, K-swizzle), else V (ch-major, V-swizzle)
  int goff[3], loff[3];
  bool isK[3];
#pragma unroll
  for (int i = 0; i < 3; ++i) {
    int chunk = tid + 512 * i;
    if (chunk < 768) {
      int key = chunk / 6, part = chunk - key * 6;
      isK[i] = true;
      goff[i] = key * 48 + part * 8;
      loff[i] = (key * 96 + part * 16) ^ ((key & 7) << 4);
    } else {
      int cv = chunk - 768;
      int c2 = cv >> 4, kp = cv & 15;
      isK[i] = false;
      goff[i] = c2 * NPIX + kp * 8;
      loff[i] = 12288 + ((c2 * 256 + kp * 16) ^ ((c2 & 15) << 4));
    }
  }

  // Vt pad rows 48..63 for BOTH buffers: row 48 = ones (den), rest zero.
  {
    int b = tid >> 8, j = tid & 255;
    int c = 48 + (j >> 4), kp = j & 15;
    unsigned short val = (c == 48) ? (unsigned short)0x3F80 : (unsigned short)0;
    ushort8v vv = {val, val, val, val, val, val, val, val};
    *(ushort8v*)(smem + b * 28672 + 12288 + ((c * 256 + kp * 16) ^ ((c & 15) << 4))) = vv;
  }
  // prologue: stage tile 0 into buffer 0
  {
    const int m0 = ks * 2048;
#pragma unroll
    for (int i = 0; i < 3; ++i) {
      short8v v = isK[i] ? *(const short8v*)(kn + m0 * 48 + goff[i])
                         : *(const short8v*)(vb + m0 + goff[i]);
      *(short8v*)(smem + loff[i]) = v;
    }
  }
  __syncthreads();

  for (int t = 0; t < 16; ++t) {
    char* buf = smem + (t & 1) * 28672;
    char* nbuf = smem + ((t + 1) & 1) * 28672;
    // ---- T14 issue-early: global loads for tile t+1 into registers ----
    short8v pf[3];
    const bool hasNext = (t + 1 < 16);
    if (hasNext) {
      const int m0n = ks * 2048 + (t + 1) * 128;
#pragma unroll
      for (int i = 0; i < 3; ++i)
        pf[i] = isK[i] ? *(const short8v*)(kn + m0n * 48 + goff[i])
                       : *(const short8v*)(vb + m0n + goff[i]);
    }
    // ---- compute tile t from buf (inner loop byte-identical to frozen) ----
#pragma unroll
    for (int kb = 0; kb < 128; kb += 32) {
      f32x16 sacc;
#pragma unroll
      for (int r = 0; r < 16; ++r) sacc[r] = 0.f;
      int key = kb + l31;
#pragma unroll
      for (int s = 0; s < 3; ++s) {
        short8v kf = *(const short8v*)(buf +
            ((key * 96 + s * 32 + lh * 16) ^ ((key & 7) << 4)));
        sacc = __builtin_amdgcn_mfma_f32_32x32x16_bf16(kf, qf[s], sacc, 0, 0, 0);
      }
      float p[16];
#pragma unroll
      for (int r = 0; r < 16; ++r) p[r] = __builtin_amdgcn_exp2f(sacc[r]);
#pragma unroll
      for (int h = 0; h < 2; ++h) {
        unsigned a0, a1, b0, b1;
        asm("v_cvt_pk_bf16_f32 %0, %1, %2" : "=v"(a0) : "v"(p[8 * h + 0]), "v"(p[8 * h + 1]));
        asm("v_cvt_pk_bf16_f32 %0, %1, %2" : "=v"(a1) : "v"(p[8 * h + 2]), "v"(p[8 * h + 3]));
        asm("v_cvt_pk_bf16_f32 %0, %1, %2" : "=v"(b0) : "v"(p[8 * h + 4]), "v"(p[8 * h + 5]));
        asm("v_cvt_pk_bf16_f32 %0, %1, %2" : "=v"(b1) : "v"(p[8 * h + 6]), "v"(p[8 * h + 7]));
        uint2v s0 = __builtin_amdgcn_permlane32_swap(a0, b0, false, false);
        uint2v s1 = __builtin_amdgcn_permlane32_swap(a1, b1, false, false);
        union { unsigned u[4]; short8v v; } pa;
        pa.u[0] = s0[0]; pa.u[1] = s1[0]; pa.u[2] = s0[1]; pa.u[3] = s1[1];
        int kbase = kb + 16 * h + 8 * lh;
        short8v vf0 = *(const short8v*)(buf + 12288 +
            ((l31 * 256 + kbase * 2) ^ ((l31 & 15) << 4)));
        acc[0] = __builtin_amdgcn_mfma_f32_32x32x16_bf16(pa.v, vf0, acc[0], 0, 0, 0);
        int c1 = 32 + l31;
        short8v vf1 = *(const short8v*)(buf + 12288 +
            ((c1 * 256 + kbase * 2) ^ ((c1 & 15) << 4)));
        acc[1] = __builtin_amdgcn_mfma_f32_32x32x16_bf16(pa.v, vf1, acc[1], 0, 0, 0);
      }
    }
    // ---- write prefetch into the OTHER buffer (disjoint; no barrier) ----
    if (hasNext) {
#pragma unroll
      for (int i = 0; i < 3; ++i)
        *(short8v*)(nbuf + loff[i]) = pf[i];
    }
    __syncthreads();  // single barrier: write(nbuf) visible before read(nbuf)
  }

  // ---- epilogue: per-wave-private transpose region, atomic-accumulate ----
  __syncthreads();
  float* ot = (float*)smem + wid * (32 * 52);   // 8 x 6656 B = 53248 <= 57344
#pragma unroll
  for (int r = 0; r < 16; ++r) {
    int q = (r & 3) + 8 * (r >> 2) + 4 * lh;
    ot[q * 52 + l31] = acc[0][r];
    if (l31 < 17) ot[q * 52 + 32 + l31] = acc[1][r];
  }
  __syncthreads();
  for (int idx = lane; idx < 49 * 32; idx += 64) {
    int q = idx & 31, c = idx >> 5;
    atomicAdd(&numS[(c << 14) + qbase + q], ot[q * 52 + c]);
  }
}

// ---------------- kernel 5: divide + proj from accumulated numS -> d_out
__global__ __launch_bounds__(256) void k_proj(const float* __restrict__ numS,
                                              const float* __restrict__ w,
                                              float* __restrict__ out) {
  __shared__ float wl[48][48];
  __shared__ float tok[48][64];
  __shared__ float dinv[64];
  const int t = threadIdx.x;
  const int px = t & 63, grp = t >> 6;
  const int p0 = blockIdx.x * 64;
  for (int i = t; i < 48 * 48; i += 256) wl[i / 48][i % 48] = w[i];
#pragma unroll
  for (int i = 0; i < 12; ++i) {
    int c = grp * 12 + i;
    tok[c][px] = numS[(c << 14) + p0 + px];
  }
  if (grp == 0) dinv[px] = 1.f / numS[(48 << 14) + p0 + px];
  __syncthreads();
  float rd = dinv[px];
#pragma unroll
  for (int i = 0; i < 12; ++i) {
    int o = grp * 12 + i;
    float a = 0.f;
#pragma unroll
    for (int c = 0; c < 48; ++c) a += wl[o][c] * tok[c][px];
    out[o * NPIX + p0 + px] = a * rd;
  }
}

extern "C" void kernel_launch(void* const* d_in, const int* in_sizes, int n_in,
                              void* d_out, int out_size, void* d_ws, size_t ws_size,
                              hipStream_t stream) {
  const float* x      = (const float*)d_in[0];
  const float* qkv_w  = (const float*)d_in[1];
  const float* dw_w   = (const float*)d_in[2];
  const float* proj_w = (const float*)d_in[3];
  const float* temp   = (const float*)d_in[4];

  // workspace layout (bytes), peak ~11.1 MB:
  //   qn   bf16 [16384][48] @ 0         (dead after attn)
  //   kn   bf16 [16384][48] @ 1572864   (dead after attn)
  //   dwqb bf16 [144][16384] @ 3145728  (ch 96..143 = vb, live in attn)
  //   qkvb bf16 [144][16384] @ 7864320  (dead after dwconv)
  //   numS f32  [49][16384] @ 7864320   (memset after dwconv; overlays qkvb)
  char* wsb = (char*)d_ws;
  unsigned short* qn   = (unsigned short*)wsb;
  unsigned short* kn   = (unsigned short*)(wsb + 1572864);
  unsigned short* dwqb = (unsigned short*)(wsb + 3145728);
  unsigned short* vb   = dwqb + 96 * NPIX;
  unsigned short* qkvb = (unsigned short*)(wsb + 7864320);
  float* numS = (float*)(wsb + 7864320);

  k_qkv<<<dim3(64, 9), 256, 0, stream>>>(x, qkv_w, qkvb);
  k_dwconv<<<dim3(8, 144), 256, 0, stream>>>(qkvb, dw_w, dwqb);
  k_norm<<<dim3(256), 128, 0, stream>>>(dwqb, temp, qn, kn);
  hipMemsetAsync(numS, 0, (size_t)49 * NPIX * 4, stream);
  k_attn8<<<dim3(512), 512, 0, stream>>>(qn, kn, vb, numS);
  k_proj<<<dim3(256), 256, 0, stream>>>(numS, proj_w, (float*)d_out);
}

// Round 25
// 110.863 us; speedup vs baseline: 1.3959x; 1.0029x over previous
//
#include <hip/hip_runtime.h>
#include <hip/hip_bf16.h>

#define NPIX 16384   // H*W
#define NC   48      // DIM

typedef __attribute__((ext_vector_type(16))) float f32x16;
typedef __attribute__((ext_vector_type(8))) short short8v;
typedef __attribute__((ext_vector_type(8))) unsigned short ushort8v;
typedef __attribute__((ext_vector_type(2))) unsigned int uint2v;

static __device__ __forceinline__ unsigned short f2bf(float x) {
  union { float f; unsigned u; } v; v.f = x;
  unsigned r = v.u + 0x7fffu + ((v.u >> 16) & 1u);
  return (unsigned short)(r >> 16);
}
static __device__ __forceinline__ float bf2f(unsigned short b) {
  union { unsigned u; float f; } v; v.u = ((unsigned)b) << 16;
  return v.f;
}

// ---------------- kernel 1: pointwise qkv conv -> bf16 channel-major.
__global__ __launch_bounds__(256) void k_qkv(const float* __restrict__ in,
                                             const float* __restrict__ w,
                                             unsigned short* __restrict__ out) {
  int p = blockIdx.x * 256 + threadIdx.x;
  int og = blockIdx.y * 16;
  __shared__ float wl[16][NC];
  for (int i = threadIdx.x; i < 16 * NC; i += 256)
    wl[i / NC][i % NC] = w[(og + i / NC) * NC + i % NC];
  __syncthreads();
  float acc[16];
#pragma unroll
  for (int j = 0; j < 16; ++j) acc[j] = 0.f;
  for (int c = 0; c < NC; ++c) {
    float xv = in[c * NPIX + p];
#pragma unroll
    for (int j = 0; j < 16; ++j) acc[j] += xv * wl[j][c];
  }
#pragma unroll
  for (int j = 0; j < 16; ++j) out[(og + j) * NPIX + p] = f2bf(acc[j]);
}

// ---------------- kernel 2: depthwise 3x3 (bf16), LDS-tiled + vectorized.
__global__ __launch_bounds__(256) void k_dwconv(const unsigned short* __restrict__ in,
                                                const float* __restrict__ w,
                                                unsigned short* __restrict__ out) {
  __shared__ unsigned short srows[18][136];
  const int o = blockIdx.y;
  const int by = blockIdx.x;   // row-tile 0..7
  const int tid = threadIdx.x;
  const float* wt = w + o * 9;
  for (int idx = tid; idx < 288; idx += 256) {
    int r = idx >> 4, cx = idx & 15;
    int gy = by * 16 + r - 1;
    ushort8v vv = {0, 0, 0, 0, 0, 0, 0, 0};
    if (gy >= 0 && gy < 128)
      vv = *(const ushort8v*)(in + o * NPIX + gy * 128 + cx * 8);
    *(ushort8v*)&srows[r][cx * 8] = vv;
  }
  __syncthreads();
  const int r = tid >> 4;            // output row within tile, 0..15
  const int x0 = (tid & 15) * 8;     // first of 8 output cols
  float row[3][10];
#pragma unroll
  for (int dy = 0; dy < 3; ++dy) {
    int lr = r + dy;
    ushort8v mid = *(const ushort8v*)&srows[lr][x0];
#pragma unroll
    for (int j = 0; j < 8; ++j) row[dy][j + 1] = bf2f(mid[j]);
    row[dy][0] = (x0 > 0) ? bf2f(srows[lr][x0 - 1]) : 0.f;
    row[dy][9] = (x0 + 8 < 128) ? bf2f(srows[lr][x0 + 8]) : 0.f;
  }
  float wv[9];
#pragma unroll
  for (int i = 0; i < 9; ++i) wv[i] = wt[i];
  unsigned short res[8];
#pragma unroll
  for (int j = 0; j < 8; ++j) {
    float acc = 0.f;
#pragma unroll
    for (int dy = 0; dy < 3; ++dy)
#pragma unroll
      for (int dx = 0; dx < 3; ++dx)
        acc += wv[dy * 3 + dx] * row[dy][j + dx];
    res[j] = f2bf(acc);
  }
  int gy = by * 16 + r;
  *(ushort8v*)(out + o * NPIX + gy * 128 + x0) = *(ushort8v*)res;
}

// ---------------- kernel 3: l2norm, q/k split; grid 256 x 128 thr.
__global__ __launch_bounds__(128) void k_norm(const unsigned short* __restrict__ dwqb,
                                              const float* __restrict__ temp,
                                              unsigned short* __restrict__ qn,
                                              unsigned short* __restrict__ kn) {
  const int tid = threadIdx.x;
  const int p = blockIdx.x * 64 + (tid & 63);
  const int half = tid >> 6;  // 0: q, 1: k
  float t = temp[0] * 1.44269504088896f;
  const unsigned short* src = dwqb + half * 48 * NPIX;
  float v[48];
  float sq = 0.f;
#pragma unroll
  for (int c = 0; c < 48; ++c) {
    v[c] = bf2f(src[c * NPIX + p]);
    sq += v[c] * v[c];
  }
  float scale = (half == 0 ? t : 1.f) / fmaxf(sqrtf(sq), 1e-12f);
  unsigned short ob[48];
#pragma unroll
  for (int c = 0; c < 48; ++c) ob[c] = f2bf(v[c] * scale);
  unsigned short* dst = (half == 0 ? qn : kn) + p * 48;
#pragma unroll
  for (int j = 0; j < 6; ++j)
    *(ushort8v*)(dst + j * 8) = *(ushort8v*)&ob[j * 8];
}

// ---------------- kernel 4: MFMA attention — EXACT r22-verified kernel
// (73.7 us, absmax 5.7e-6): 8 uniform waves (512 thr, plain launch_bounds),
// 256 q-rows/block, NS=8, double-buffer + 1 barrier/tile, atomic epilogue.
// FROZEN. Failure ledger (all ~1e-4 corruption; do NOT re-attempt):
//   r2/r4/r8: launch_bounds(,N) clause      r14: s_setprio
//   r23: single-buffer same-buffer-write @512thr + NS=16 + 2-pass epilogue
// Common factor: large codegen shifts around the inline-asm
// cvt_pk/permlane/MFMA cluster trip an unhandleable hazard. This schedule
// is the verified optimum; r16 proved the asm cluster itself is required.
__global__ __launch_bounds__(512) void k_attn8(const unsigned short* __restrict__ qn,
                                               const unsigned short* __restrict__ kn,
                                               const unsigned short* __restrict__ vb,
                                               float* __restrict__ numS) {
  __shared__ __align__(16) char smem[57344];  // 2 x (K 12288 B + Vt 16384 B)
  const int tid = threadIdx.x;
  const int lane = tid & 63, wid = tid >> 6;   // wid 0..7
  const int l31 = lane & 31, lh = lane >> 5;
  const int bidx = blockIdx.x;
  const int ks = bidx & 7;
  const int qb = bidx >> 3;
  const int qbase = qb * 256 + wid * 32;

  short8v qf[3];
#pragma unroll
  for (int s = 0; s < 3; ++s)
    qf[s] = *(const short8v*)(qn + (qbase + l31) * 48 + s * 16 + lh * 8);

  f32x16 acc[2];  // [c-block]
#pragma unroll
  for (int b = 0; b < 2; ++b)
#pragma unroll
    for (int r = 0; r < 16; ++r) acc[b][r] = 0.f;

  // t-invariant staging maps: 1536 16B-chunks over 512 threads (3 each);
  // chunk<768 -> K (token-major, K-swizzle), else V (ch-major, V-swizzle)
  int goff[3], loff[3];
  bool isK[3];
#pragma unroll
  for (int i = 0; i < 3; ++i) {
    int chunk = tid + 512 * i;
    if (chunk < 768) {
      int key = chunk / 6, part = chunk - key * 6;
      isK[i] = true;
      goff[i] = key * 48 + part * 8;
      loff[i] = (key * 96 + part * 16) ^ ((key & 7) << 4);
    } else {
      int cv = chunk - 768;
      int c2 = cv >> 4, kp = cv & 15;
      isK[i] = false;
      goff[i] = c2 * NPIX + kp * 8;
      loff[i] = 12288 + ((c2 * 256 + kp * 16) ^ ((c2 & 15) << 4));
    }
  }

  // Vt pad rows 48..63 for BOTH buffers: row 48 = ones (den), rest zero.
  {
    int b = tid >> 8, j = tid & 255;
    int c = 48 + (j >> 4), kp = j & 15;
    unsigned short val = (c == 48) ? (unsigned short)0x3F80 : (unsigned short)0;
    ushort8v vv = {val, val, val, val, val, val, val, val};
    *(ushort8v*)(smem + b * 28672 + 12288 + ((c * 256 + kp * 16) ^ ((c & 15) << 4))) = vv;
  }
  // prologue: stage tile 0 into buffer 0
  {
    const int m0 = ks * 2048;
#pragma unroll
    for (int i = 0; i < 3; ++i) {
      short8v v = isK[i] ? *(const short8v*)(kn + m0 * 48 + goff[i])
                         : *(const short8v*)(vb + m0 + goff[i]);
      *(short8v*)(smem + loff[i]) = v;
    }
  }
  __syncthreads();

  for (int t = 0; t < 16; ++t) {
    char* buf = smem + (t & 1) * 28672;
    char* nbuf = smem + ((t + 1) & 1) * 28672;
    // ---- T14 issue-early: global loads for tile t+1 into registers ----
    short8v pf[3];
    const bool hasNext = (t + 1 < 16);
    if (hasNext) {
      const int m0n = ks * 2048 + (t + 1) * 128;
#pragma unroll
      for (int i = 0; i < 3; ++i)
        pf[i] = isK[i] ? *(const short8v*)(kn + m0n * 48 + goff[i])
                       : *(const short8v*)(vb + m0n + goff[i]);
    }
    // ---- compute tile t from buf (inner loop byte-identical to frozen) ----
#pragma unroll
    for (int kb = 0; kb < 128; kb += 32) {
      f32x16 sacc;
#pragma unroll
      for (int r = 0; r < 16; ++r) sacc[r] = 0.f;
      int key = kb + l31;
#pragma unroll
      for (int s = 0; s < 3; ++s) {
        short8v kf = *(const short8v*)(buf +
            ((key * 96 + s * 32 + lh * 16) ^ ((key & 7) << 4)));
        sacc = __builtin_amdgcn_mfma_f32_32x32x16_bf16(kf, qf[s], sacc, 0, 0, 0);
      }
      float p[16];
#pragma unroll
      for (int r = 0; r < 16; ++r) p[r] = __builtin_amdgcn_exp2f(sacc[r]);
#pragma unroll
      for (int h = 0; h < 2; ++h) {
        unsigned a0, a1, b0, b1;
        asm("v_cvt_pk_bf16_f32 %0, %1, %2" : "=v"(a0) : "v"(p[8 * h + 0]), "v"(p[8 * h + 1]));
        asm("v_cvt_pk_bf16_f32 %0, %1, %2" : "=v"(a1) : "v"(p[8 * h + 2]), "v"(p[8 * h + 3]));
        asm("v_cvt_pk_bf16_f32 %0, %1, %2" : "=v"(b0) : "v"(p[8 * h + 4]), "v"(p[8 * h + 5]));
        asm("v_cvt_pk_bf16_f32 %0, %1, %2" : "=v"(b1) : "v"(p[8 * h + 6]), "v"(p[8 * h + 7]));
        uint2v s0 = __builtin_amdgcn_permlane32_swap(a0, b0, false, false);
        uint2v s1 = __builtin_amdgcn_permlane32_swap(a1, b1, false, false);
        union { unsigned u[4]; short8v v; } pa;
        pa.u[0] = s0[0]; pa.u[1] = s1[0]; pa.u[2] = s0[1]; pa.u[3] = s1[1];
        int kbase = kb + 16 * h + 8 * lh;
        short8v vf0 = *(const short8v*)(buf + 12288 +
            ((l31 * 256 + kbase * 2) ^ ((l31 & 15) << 4)));
        acc[0] = __builtin_amdgcn_mfma_f32_32x32x16_bf16(pa.v, vf0, acc[0], 0, 0, 0);
        int c1 = 32 + l31;
        short8v vf1 = *(const short8v*)(buf + 12288 +
            ((c1 * 256 + kbase * 2) ^ ((c1 & 15) << 4)));
        acc[1] = __builtin_amdgcn_mfma_f32_32x32x16_bf16(pa.v, vf1, acc[1], 0, 0, 0);
      }
    }
    // ---- write prefetch into the OTHER buffer (disjoint; no barrier) ----
    if (hasNext) {
#pragma unroll
      for (int i = 0; i < 3; ++i)
        *(short8v*)(nbuf + loff[i]) = pf[i];
    }
    __syncthreads();  // single barrier: write(nbuf) visible before read(nbuf)
  }

  // ---- epilogue: per-wave-private transpose region, atomic-accumulate ----
  __syncthreads();
  float* ot = (float*)smem + wid * (32 * 52);   // 8 x 6656 B = 53248 <= 57344
#pragma unroll
  for (int r = 0; r < 16; ++r) {
    int q = (r & 3) + 8 * (r >> 2) + 4 * lh;
    ot[q * 52 + l31] = acc[0][r];
    if (l31 < 17) ot[q * 52 + 32 + l31] = acc[1][r];
  }
  __syncthreads();
  for (int idx = lane; idx < 49 * 32; idx += 64) {
    int q = idx & 31, c = idx >> 5;
    atomicAdd(&numS[(c << 14) + qbase + q], ot[q * 52 + c]);
  }
}

// ---------------- kernel 5: divide + proj from accumulated numS -> d_out
__global__ __launch_bounds__(256) void k_proj(const float* __restrict__ numS,
                                              const float* __restrict__ w,
                                              float* __restrict__ out) {
  __shared__ float wl[48][48];
  __shared__ float tok[48][64];
  __shared__ float dinv[64];
  const int t = threadIdx.x;
  const int px = t & 63, grp = t >> 6;
  const int p0 = blockIdx.x * 64;
  for (int i = t; i < 48 * 48; i += 256) wl[i / 48][i % 48] = w[i];
#pragma unroll
  for (int i = 0; i < 12; ++i) {
    int c = grp * 12 + i;
    tok[c][px] = numS[(c << 14) + p0 + px];
  }
  if (grp == 0) dinv[px] = 1.f / numS[(48 << 14) + p0 + px];
  __syncthreads();
  float rd = dinv[px];
#pragma unroll
  for (int i = 0; i < 12; ++i) {
    int o = grp * 12 + i;
    float a = 0.f;
#pragma unroll
    for (int c = 0; c < 48; ++c) a += wl[o][c] * tok[c][px];
    out[o * NPIX + p0 + px] = a * rd;
  }
}

extern "C" void kernel_launch(void* const* d_in, const int* in_sizes, int n_in,
                              void* d_out, int out_size, void* d_ws, size_t ws_size,
                              hipStream_t stream) {
  const float* x      = (const float*)d_in[0];
  const float* qkv_w  = (const float*)d_in[1];
  const float* dw_w   = (const float*)d_in[2];
  const float* proj_w = (const float*)d_in[3];
  const float* temp   = (const float*)d_in[4];

  // workspace layout (bytes), peak ~11.1 MB:
  //   qn   bf16 [16384][48] @ 0         (dead after attn)
  //   kn   bf16 [16384][48] @ 1572864   (dead after attn)
  //   dwqb bf16 [144][16384] @ 3145728  (ch 96..143 = vb, live in attn)
  //   qkvb bf16 [144][16384] @ 7864320  (dead after dwconv)
  //   numS f32  [49][16384] @ 7864320   (memset after dwconv; overlays qkvb)
  char* wsb = (char*)d_ws;
  unsigned short* qn   = (unsigned short*)wsb;
  unsigned short* kn   = (unsigned short*)(wsb + 1572864);
  unsigned short* dwqb = (unsigned short*)(wsb + 3145728);
  unsigned short* vb   = dwqb + 96 * NPIX;
  unsigned short* qkvb = (unsigned short*)(wsb + 7864320);
  float* numS = (float*)(wsb + 7864320);

  k_qkv<<<dim3(64, 9), 256, 0, stream>>>(x, qkv_w, qkvb);
  k_dwconv<<<dim3(8, 144), 256, 0, stream>>>(qkvb, dw_w, dwqb);
  k_norm<<<dim3(256), 128, 0, stream>>>(dwqb, temp, qn, kn);
  hipMemsetAsync(numS, 0, (size_t)49 * NPIX * 4, stream);
  k_attn8<<<dim3(512), 512, 0, stream>>>(qn, kn, vb, numS);
  k_proj<<<dim3(256), 256, 0, stream>>>(numS, proj_w, (float*)d_out);
}